// Round 2
// baseline (2243.358 us; speedup 1.0000x reference)
//
#include <hip/hip_runtime.h>

#define Nn 50000
#define Ee 800000
#define STEPSn 6

typedef _Float16 half8 __attribute__((ext_vector_type(8)));
typedef _Float16 half4v __attribute__((ext_vector_type(4)));
typedef float floatx4 __attribute__((ext_vector_type(4)));

typedef __attribute__((address_space(1))) void gvoid_t;
typedef __attribute__((address_space(3))) void svoid_t;

__device__ __forceinline__ float leakyf(float v) { return v > 0.f ? v : 0.2f * v; }

__device__ __forceinline__ void gload16(const void* g, void* l) {
    __builtin_amdgcn_global_load_lds((const gvoid_t*)g, (svoid_t*)l, 16, 0, 0);
}

// ---------------- CSR build ----------------
__global__ void k_count(const int* __restrict__ dst, int* __restrict__ cnt) {
    int e = blockIdx.x * 256 + threadIdx.x;
    if (e < Ee) atomicAdd(&cnt[dst[e]], 1);
}

__global__ void k_scan(const int* __restrict__ cnt, int* __restrict__ off) {
    __shared__ int part[256];
    int t = threadIdx.x;
    const int chunk = (Nn + 255) / 256;
    int beg = t * chunk, end = beg + chunk;
    if (end > Nn) end = Nn;
    if (beg > Nn) beg = Nn;
    int s = 0;
    for (int i = beg; i < end; ++i) s += cnt[i];
    part[t] = s;
    __syncthreads();
    if (t == 0) {
        int run = 0;
        for (int i = 0; i < 256; ++i) { int v = part[i]; part[i] = run; run += v; }
        off[Nn] = run;
    }
    __syncthreads();
    int run = part[t];
    for (int i = beg; i < end; ++i) { off[i] = run; run += cnt[i]; }
}

// fill CSR slots: packed (src | lt<<20) + permuted edge_attr scalar
__global__ void k_fill(const int* __restrict__ src, const int* __restrict__ dst,
                       const float* __restrict__ edge_attr, const int* __restrict__ link_type,
                       const int* __restrict__ off, int* __restrict__ cur,
                       int* __restrict__ src_p, float* __restrict__ tperm) {
    int e = blockIdx.x * 256 + threadIdx.x;
    if (e >= Ee) return;
    int d = dst[e];
    int slot = off[d] + atomicAdd(&cur[d], 1);
    src_p[slot] = src[e] | (link_type[e] << 20);
    tperm[slot] = edge_attr[e];
}

// ---------------- tiny per-launch constants ----------------
// C layout: [0:8] attP, [8:16] attM, [16:40] etA (3x8), [40:72] linP, [72:104] linM
__global__ void k_const(const float* __restrict__ Et, const float* __restrict__ Wea,
                        const float* __restrict__ Watt, const float* __restrict__ Wlin,
                        float* __restrict__ C) {
    __shared__ float u[50], v[50];
    int t = threadIdx.x;
    if (t < 50) {
        float w = Wea[t];
        u[t] = w * (w > 0.f ? 1.f : 0.2f);
        v[t] = w * (w < 0.f ? 1.f : 0.2f);
    }
    __syncthreads();
    if (t < 8) {
        float a = 0.f, b = 0.f;
        for (int j = 0; j < 50; ++j) {
            float w = Watt[(74 + j) * 8 + t];
            a += u[j] * w;
            b += v[j] * w;
        }
        C[t] = a;
        C[8 + t] = b;
    } else if (t < 32) {
        int lt = (t - 8) >> 3, h = (t - 8) & 7;
        float a = 0.f;
        for (int j = 0; j < 10; ++j) a += leakyf(Et[lt * 10 + j]) * Watt[(64 + j) * 8 + h];
        C[16 + (t - 8)] = a;
    } else if (t < 64) {
        int c = t - 32;
        float a = 0.f, b = 0.f;
        for (int j = 0; j < 50; ++j) {
            float w = Wlin[(32 + j) * 32 + c];
            a += u[j] * w;
            b += v[j] * w;
        }
        C[40 + c] = a;
        C[72 + c] = b;
    }
}

// ---------------- weight transpose+convert (fp32 [K][NN] -> fp16 [NN][K], 6 steps) ------
__global__ void k_wtrans(const float* __restrict__ W, _Float16* __restrict__ WT,
                         int K, int NN) {
    long t = (long)blockIdx.x * 256 + threadIdx.x;
    long per = (long)K * NN;
    if (t >= (long)STEPSn * per) return;
    int s = (int)(t / per);
    long r = t % per;
    int k = (int)(r / NN), n = (int)(r % NN);
    WT[s * per + (long)n * K + k] = (_Float16)W[t];
}

// ---------------- per-node projections ----------------
__global__ __launch_bounds__(256) void k_node_proj(
    const float* __restrict__ m, const int* __restrict__ node_type,
    const float* __restrict__ Wh, const float* __restrict__ bh,
    const float* __restrict__ Watt, const float* __restrict__ Wlin,
    float* __restrict__ adst, float* __restrict__ asrc, _Float16* __restrict__ xlin) {
    __shared__ float sm[8][256];
    __shared__ float sx[8][32];
    int n0 = blockIdx.x * 8;
    for (int i = threadIdx.x; i < 8 * 256; i += 256) sm[i >> 8][i & 255] = m[(long)n0 * 256 + i];
    __syncthreads();
    int nl = threadIdx.x >> 5, c = threadIdx.x & 31;
    int ty = (node_type[n0 + nl] == 0) ? 0 : 1;
    const float* W = Wh + ty * (256 * 32);
    float acc = bh[ty * 32 + c];
#pragma unroll 8
    for (int k = 0; k < 256; ++k) acc += sm[nl][k] * W[k * 32 + c];
    sx[nl][c] = acc;
    __syncthreads();
    float xl = 0.f;
#pragma unroll 8
    for (int cc = 0; cc < 32; ++cc) xl += sx[nl][cc] * Wlin[cc * 32 + c];
    xlin[(long)(n0 + nl) * 32 + c] = (_Float16)xl;
    if (threadIdx.x < 64) {
        int nl2 = threadIdx.x >> 3, h = threadIdx.x & 7;
        float a1 = 0.f, a2 = 0.f;
#pragma unroll 8
        for (int cc = 0; cc < 32; ++cc) {
            float xv = sx[nl2][cc];
            a1 += xv * Watt[cc * 8 + h];
            a2 += xv * Watt[(32 + cc) * 8 + h];
        }
        adst[(long)(n0 + nl2) * 8 + h] = a1;
        asrc[(long)(n0 + nl2) * 8 + h] = a2;
    }
}

// ---------------- edge aggregation + LN1 (one wave per node) ----------------
__global__ __launch_bounds__(256) void k_edge_ln1(
    const int* __restrict__ off, const int* __restrict__ src_p,
    const float* __restrict__ tperm, const float* __restrict__ C,
    const float* __restrict__ adst, const float* __restrict__ asrc,
    const _Float16* __restrict__ xlin, const float* __restrict__ m_in,
    const float* __restrict__ g1, const float* __restrict__ b1,
    _Float16* __restrict__ m1h) {
    __shared__ float sC[104];
    if (threadIdx.x < 104) sC[threadIdx.x] = C[threadIdx.x];
    __syncthreads();
    int n = blockIdx.x * 4 + (threadIdx.x >> 6);
    int lane = threadIdx.x & 63;
    long base = off[n];
    int deg = off[n + 1] - (int)base;
    int h = lane & 7;
    float adst_h = adst[(long)n * 8 + h];
    // pass 1: per-head max (8 edges x 8 heads per iteration)
    float mx = -1e30f;
    for (int i = lane >> 3; i < deg; i += 8) {
        long ei = base + i;
        int p = src_p[ei];
        int s = p & 0xFFFFF, lt = p >> 20;
        float t = tperm[ei];
        float attc = sC[16 + lt * 8 + h] + t * (t > 0.f ? sC[h] : sC[8 + h]);
        float lg = leakyf(adst_h + asrc[(long)s * 8 + h] + attc);
        mx = fmaxf(mx, lg);
    }
    mx = fmaxf(mx, __shfl_xor(mx, 8));
    mx = fmaxf(mx, __shfl_xor(mx, 16));
    mx = fmaxf(mx, __shfl_xor(mx, 32));
    // pass 2: accumulate sum(exp) and sum(exp * msg); 2 edges/iter (half-wave each)
    int hv = lane >> 5, lc = lane & 31;
    float linP = sC[40 + lc], linM = sC[72 + lc];
    float ssum = 0.f;
    float acc[8] = {0.f, 0.f, 0.f, 0.f, 0.f, 0.f, 0.f, 0.f};
    int deg2 = (deg + 1) & ~1;
    for (int i2 = hv; i2 < deg2; i2 += 2) {
        bool valid = i2 < deg;
        long ei = base + (valid ? i2 : (deg - 1));
        int p = src_p[ei];
        int s = p & 0xFFFFF, lt = p >> 20;
        float t = tperm[ei];
        float attc = sC[16 + lt * 8 + h] + t * (t > 0.f ? sC[h] : sC[8 + h]);
        float lg = adst_h + asrc[(long)s * 8 + h] + attc;
        float w = valid ? __expf(leakyf(lg) - mx) : 0.f;
        float msg = (float)xlin[(long)s * 32 + lc] + t * (t > 0.f ? linP : linM);
        if (lc < 8) ssum += w;
#pragma unroll
        for (int hh = 0; hh < 8; ++hh) {
            float whh = __shfl(w, (hv << 5) + hh);
            acc[hh] += whh * msg;
        }
    }
#pragma unroll
    for (int hh = 0; hh < 8; ++hh) acc[hh] += __shfl_xor(acc[hh], 32);
    ssum += __shfl_xor(ssum, 32);
    // normalize, add residual, LayerNorm
    float v[8];
    float s1 = 0.f, s2 = 0.f;
#pragma unroll
    for (int hh = 0; hh < 8; ++hh) {
        float sh = __shfl(ssum, hh);
        float o = acc[hh] / (sh + 1e-16f);
        float vv = o + m_in[(long)n * 256 + hh * 32 + lc];
        v[hh] = vv;
        s1 += vv;
        s2 += vv * vv;
    }
#pragma unroll
    for (int d = 1; d < 64; d <<= 1) { s1 += __shfl_xor(s1, d); s2 += __shfl_xor(s2, d); }
    float mu = s1 * (1.f / 512.f);
    float var = s2 * (1.f / 512.f) - mu * mu;
    float rs = rsqrtf(var + 1e-5f);
    if (hv == 0) {
#pragma unroll
        for (int hh = 0; hh < 8; ++hh) {
            int col = hh * 32 + lc;
            float o = (v[hh] - mu) * rs * g1[col] + b1[col];
            m1h[(long)n * 256 + col] = (_Float16)o;
        }
    }
}

// ---------------- fp16 MFMA GEMM: C = A[M,K] @ BT[NN,K]^T (+bias) ----------------
// EPI==1: relu + fp16 store; EPI==0: fp32 store
template <int EPI>
__global__ __launch_bounds__(256) void k_gemm(const _Float16* __restrict__ A,
                                              const _Float16* __restrict__ BT,
                                              const float* __restrict__ bias,
                                              void* __restrict__ out,
                                              int M, int K, int NN) {
    __shared__ _Float16 sA[128 * 64];
    __shared__ _Float16 sB[128 * 64];
    const int tid = threadIdx.x;
    const int wid = tid >> 6;
    const int lane = tid & 63;
    const int rowBase = blockIdx.y * 128;
    const int colBase = blockIdx.x * 128;
    const int srow = wid * 8 + (lane >> 3);
    const int schunk = (lane & 7) ^ ((lane >> 3) & 7);  // XOR-swizzled source chunk
    const _Float16* aSrc[4];
    const _Float16* bSrc[4];
#pragma unroll
    for (int j = 0; j < 4; ++j) {
        int r = j * 32 + srow;
        int gr = rowBase + r;
        if (gr > M - 1) gr = M - 1;
        aSrc[j] = A + (long)gr * K + schunk * 8;
        bSrc[j] = BT + (long)(colBase + r) * K + schunk * 8;
    }
    floatx4 acc[4][4];
    floatx4 zz = {0.f, 0.f, 0.f, 0.f};
#pragma unroll
    for (int i = 0; i < 4; ++i)
#pragma unroll
        for (int j = 0; j < 4; ++j) acc[i][j] = zz;
    const int wm = (wid >> 1) * 64, wn = (wid & 1) * 64;
    for (int k0 = 0; k0 < K; k0 += 64) {
#pragma unroll
        for (int j = 0; j < 4; ++j) {
            gload16(aSrc[j] + k0, &sA[(j * 32 + wid * 8) * 64]);
            gload16(bSrc[j] + k0, &sB[(j * 32 + wid * 8) * 64]);
        }
        __syncthreads();
#pragma unroll
        for (int kk = 0; kk < 2; ++kk) {
            half8 af[4], bf[4];
#pragma unroll
            for (int i = 0; i < 4; ++i) {
                int row = wm + i * 16 + (lane & 15);
                int ch = (kk * 4 + (lane >> 4)) ^ (row & 7);
                af[i] = *(const half8*)&sA[row * 64 + ch * 8];
            }
#pragma unroll
            for (int j = 0; j < 4; ++j) {
                int row = wn + j * 16 + (lane & 15);
                int ch = (kk * 4 + (lane >> 4)) ^ (row & 7);
                bf[j] = *(const half8*)&sB[row * 64 + ch * 8];
            }
#pragma unroll
            for (int i = 0; i < 4; ++i)
#pragma unroll
                for (int j = 0; j < 4; ++j)
                    acc[i][j] = __builtin_amdgcn_mfma_f32_16x16x32_f16(af[i], bf[j], acc[i][j], 0, 0, 0);
        }
        __syncthreads();
    }
#pragma unroll
    for (int j = 0; j < 4; ++j) {
        int gcol = colBase + wn + j * 16 + (lane & 15);
        float bv = bias[gcol];
#pragma unroll
        for (int i = 0; i < 4; ++i) {
#pragma unroll
            for (int q = 0; q < 4; ++q) {
                int grow = rowBase + wm + i * 16 + (lane >> 4) * 4 + q;
                if (grow < M) {
                    float vv = acc[i][j][q] + bv;
                    if (EPI == 1) {
                        vv = vv > 0.f ? vv : 0.f;
                        ((_Float16*)out)[(long)grow * NN + gcol] = (_Float16)vv;
                    } else {
                        ((float*)out)[(long)grow * NN + gcol] = vv;
                    }
                }
            }
        }
    }
}

// ---------------- LN2 (f + m1h -> out) ----------------
__global__ __launch_bounds__(256) void k_ln2(const float* __restrict__ f,
                                             const _Float16* __restrict__ m1,
                                             const float* __restrict__ g,
                                             const float* __restrict__ b,
                                             float* __restrict__ outm) {
    int n = blockIdx.x * 4 + (threadIdx.x >> 6);
    int lane = threadIdx.x & 63;
    float4 fv = ((const float4*)(f + (long)n * 256))[lane];
    half4v mv = ((const half4v*)(m1 + (long)n * 256))[lane];
    float v0 = fv.x + (float)mv[0], v1 = fv.y + (float)mv[1];
    float v2 = fv.z + (float)mv[2], v3 = fv.w + (float)mv[3];
    float s1 = v0 + v1 + v2 + v3;
    float s2 = v0 * v0 + v1 * v1 + v2 * v2 + v3 * v3;
#pragma unroll
    for (int d = 1; d < 64; d <<= 1) { s1 += __shfl_xor(s1, d); s2 += __shfl_xor(s2, d); }
    float mu = s1 * (1.f / 256.f);
    float var = s2 * (1.f / 256.f) - mu * mu;
    float rs = rsqrtf(var + 1e-5f);
    float4 gv = ((const float4*)g)[lane];
    float4 bv = ((const float4*)b)[lane];
    float4 o;
    o.x = (v0 - mu) * rs * gv.x + bv.x;
    o.y = (v1 - mu) * rs * gv.y + bv.y;
    o.z = (v2 - mu) * rs * gv.z + bv.z;
    o.w = (v3 - mu) * rs * gv.w + bv.w;
    ((float4*)(outm + (long)n * 256))[lane] = o;
}

__global__ void k_fail(float* out) {
    if (threadIdx.x == 0 && blockIdx.x == 0) out[0] = 2.0e6f;
}

extern "C" void kernel_launch(void* const* d_in, const int* in_sizes, int n_in,
                              void* d_out, int out_size, void* d_ws, size_t ws_size,
                              hipStream_t stream) {
    const float* x = (const float*)d_in[0];
    const int* ei = (const int*)d_in[1];
    const float* edge_attr = (const float*)d_in[2];
    const int* node_type = (const int*)d_in[3];
    const int* link_type = (const int*)d_in[4];
    const float* Wh = (const float*)d_in[5];
    const float* bh = (const float*)d_in[6];
    const float* Et = (const float*)d_in[7];
    const float* Wea = (const float*)d_in[8];
    const float* Watt = (const float*)d_in[9];
    const float* Wlin = (const float*)d_in[10];
    const float* ffn_w1 = (const float*)d_in[11];
    const float* ffn_b1 = (const float*)d_in[12];
    const float* ffn_w2 = (const float*)d_in[13];
    const float* ffn_b2 = (const float*)d_in[14];
    const float* ln1_g = (const float*)d_in[15];
    const float* ln1_b = (const float*)d_in[16];
    const float* ln2_g = (const float*)d_in[17];
    const float* ln2_b = (const float*)d_in[18];
    const int* srcp = ei;
    const int* dstp = ei + Ee;

    size_t o = 0;
    auto carve = [&](size_t bytes) -> void* {
        void* p = (char*)d_ws + o;
        o += (bytes + 255) & ~(size_t)255;
        return p;
    };
    // fixed buffers (~45 MB)
    _Float16* m1h = (_Float16*)carve((size_t)Nn * 256 * 2);
    float* adst = (float*)carve((size_t)Nn * 8 * 4);
    float* asrc = (float*)carve((size_t)Nn * 8 * 4);
    _Float16* xlin = (_Float16*)carve((size_t)Nn * 32 * 2);
    int* src_p = (int*)carve((size_t)Ee * 4);
    float* tperm = (float*)carve((size_t)Ee * 4);
    int* off = (int*)carve((size_t)(Nn + 1) * 4);
    int* cnt = (int*)carve((size_t)Nn * 4);
    int* cur = (int*)carve((size_t)Nn * 4);
    _Float16* W1T = (_Float16*)carve((size_t)STEPSn * 256 * 1024 * 2);
    _Float16* W2T = (_Float16*)carve((size_t)STEPSn * 256 * 1024 * 2);
    float* econst = (float*)carve(104 * 4);
    // runtime-sized FFN row chunk: 1024*2 (f1h) + 256*4 (fbuf) = 3072 B/row
    long remain = (long)ws_size - (long)o;
    long ch = remain / 3072;
    ch = (ch / 128) * 128;
    int CH = ch > Nn ? Nn : (int)ch;
    if (CH < 128) {
        k_fail<<<1, 64, 0, stream>>>((float*)d_out);
        return;
    }
    _Float16* f1h = (_Float16*)carve((size_t)CH * 1024 * 2);
    float* fbuf = (float*)carve((size_t)CH * 256 * 4);
    if (o > ws_size) {
        k_fail<<<1, 64, 0, stream>>>((float*)d_out);
        return;
    }

    hipMemsetAsync(cnt, 0, (size_t)Nn * 4, stream);
    hipMemsetAsync(cur, 0, (size_t)Nn * 4, stream);
    k_count<<<3125, 256, 0, stream>>>(dstp, cnt);
    k_scan<<<1, 256, 0, stream>>>(cnt, off);
    k_fill<<<3125, 256, 0, stream>>>(srcp, dstp, edge_attr, link_type, off, cur,
                                     src_p, tperm);
    k_const<<<1, 128, 0, stream>>>(Et, Wea, Watt, Wlin, econst);
    k_wtrans<<<6144, 256, 0, stream>>>(ffn_w1, W1T, 256, 1024);
    k_wtrans<<<6144, 256, 0, stream>>>(ffn_w2, W2T, 1024, 256);

    const float* m_in = x;
    for (int s = 0; s < STEPSn; ++s) {
        k_node_proj<<<Nn / 8, 256, 0, stream>>>(m_in, node_type, Wh, bh, Watt, Wlin,
                                                adst, asrc, xlin);
        k_edge_ln1<<<Nn / 4, 256, 0, stream>>>(off, src_p, tperm, econst, adst, asrc,
                                               xlin, m_in, ln1_g + s * 256, ln1_b + s * 256,
                                               m1h);
        for (int cs = 0; cs < Nn; cs += CH) {
            int cm = (Nn - cs) < CH ? (Nn - cs) : CH;
            k_gemm<1><<<dim3(8, (cm + 127) / 128), 256, 0, stream>>>(
                m1h + (size_t)cs * 256, W1T + (size_t)s * 262144,
                ffn_b1 + s * 1024, (void*)f1h, cm, 256, 1024);
            k_gemm<0><<<dim3(2, (cm + 127) / 128), 256, 0, stream>>>(
                f1h, W2T + (size_t)s * 262144,
                ffn_b2 + s * 256, (void*)fbuf, cm, 1024, 256);
            k_ln2<<<cm / 4, 256, 0, stream>>>(fbuf, m1h + (size_t)cs * 256,
                                              ln2_g + s * 256, ln2_b + s * 256,
                                              (float*)d_out + (size_t)cs * 256);
        }
        m_in = (const float*)d_out;
    }
}

// Round 3
// 1741.871 us; speedup vs baseline: 1.2879x; 1.2879x over previous
//
#include <hip/hip_runtime.h>

#define Nn 50000
#define Ee 800000
#define STEPSn 6

typedef _Float16 half8 __attribute__((ext_vector_type(8)));
typedef _Float16 half4v __attribute__((ext_vector_type(4)));
typedef float floatx4 __attribute__((ext_vector_type(4)));

typedef __attribute__((address_space(1))) void gvoid_t;
typedef __attribute__((address_space(3))) void svoid_t;

__device__ __forceinline__ float leakyf(float v) { return v > 0.f ? v : 0.2f * v; }

__device__ __forceinline__ void gload16(const void* g, void* l) {
    __builtin_amdgcn_global_load_lds((const gvoid_t*)g, (svoid_t*)l, 16, 0, 0);
}

// ---------------- CSR build ----------------
__global__ void k_count(const int* __restrict__ dst, int* __restrict__ cnt) {
    int e = blockIdx.x * 256 + threadIdx.x;
    if (e < Ee) atomicAdd(&cnt[dst[e]], 1);
}

__global__ void k_scan(const int* __restrict__ cnt, int* __restrict__ off) {
    __shared__ int part[256];
    int t = threadIdx.x;
    const int chunk = (Nn + 255) / 256;
    int beg = t * chunk, end = beg + chunk;
    if (end > Nn) end = Nn;
    if (beg > Nn) beg = Nn;
    int s = 0;
    for (int i = beg; i < end; ++i) s += cnt[i];
    part[t] = s;
    __syncthreads();
    if (t == 0) {
        int run = 0;
        for (int i = 0; i < 256; ++i) { int v = part[i]; part[i] = run; run += v; }
        off[Nn] = run;
    }
    __syncthreads();
    int run = part[t];
    for (int i = beg; i < end; ++i) { off[i] = run; run += cnt[i]; }
}

// fill CSR slots: packed (src | lt<<20) + permuted edge_attr scalar
__global__ void k_fill(const int* __restrict__ src, const int* __restrict__ dst,
                       const float* __restrict__ edge_attr, const int* __restrict__ link_type,
                       const int* __restrict__ off, int* __restrict__ cur,
                       int* __restrict__ src_p, float* __restrict__ tperm) {
    int e = blockIdx.x * 256 + threadIdx.x;
    if (e >= Ee) return;
    int d = dst[e];
    int slot = off[d] + atomicAdd(&cur[d], 1);
    src_p[slot] = src[e] | (link_type[e] << 20);
    tperm[slot] = edge_attr[e];
}

// ---------------- tiny per-launch constants ----------------
// C layout: [0:8] attP, [8:16] attM, [16:40] etA (3x8), [40:72] linP, [72:104] linM
__global__ void k_const(const float* __restrict__ Et, const float* __restrict__ Wea,
                        const float* __restrict__ Watt, const float* __restrict__ Wlin,
                        float* __restrict__ C) {
    __shared__ float u[50], v[50];
    int t = threadIdx.x;
    if (t < 50) {
        float w = Wea[t];
        u[t] = w * (w > 0.f ? 1.f : 0.2f);
        v[t] = w * (w < 0.f ? 1.f : 0.2f);
    }
    __syncthreads();
    if (t < 8) {
        float a = 0.f, b = 0.f;
        for (int j = 0; j < 50; ++j) {
            float w = Watt[(74 + j) * 8 + t];
            a += u[j] * w;
            b += v[j] * w;
        }
        C[t] = a;
        C[8 + t] = b;
    } else if (t < 32) {
        int lt = (t - 8) >> 3, h = (t - 8) & 7;
        float a = 0.f;
        for (int j = 0; j < 10; ++j) a += leakyf(Et[lt * 10 + j]) * Watt[(64 + j) * 8 + h];
        C[16 + (t - 8)] = a;
    } else if (t < 64) {
        int c = t - 32;
        float a = 0.f, b = 0.f;
        for (int j = 0; j < 50; ++j) {
            float w = Wlin[(32 + j) * 32 + c];
            a += u[j] * w;
            b += v[j] * w;
        }
        C[40 + c] = a;
        C[72 + c] = b;
    }
}

// ---------------- weight transpose+convert (fp32 [K][NN] -> fp16 [NN][K], 6 steps) ------
__global__ void k_wtrans(const float* __restrict__ W, _Float16* __restrict__ WT,
                         int K, int NN) {
    long t = (long)blockIdx.x * 256 + threadIdx.x;
    long per = (long)K * NN;
    if (t >= (long)STEPSn * per) return;
    int s = (int)(t / per);
    long r = t % per;
    int k = (int)(r / NN), n = (int)(r % NN);
    WT[s * per + (long)n * K + k] = (_Float16)W[t];
}

// ---------------- per-node projections ----------------
__global__ __launch_bounds__(256) void k_node_proj(
    const float* __restrict__ m, const int* __restrict__ node_type,
    const float* __restrict__ Wh, const float* __restrict__ bh,
    const float* __restrict__ Watt, const float* __restrict__ Wlin,
    float* __restrict__ adst, float* __restrict__ asrc, _Float16* __restrict__ xlin) {
    __shared__ float sm[8][256];
    __shared__ float sx[8][32];
    int n0 = blockIdx.x * 8;
    for (int i = threadIdx.x; i < 8 * 256; i += 256) sm[i >> 8][i & 255] = m[(long)n0 * 256 + i];
    __syncthreads();
    int nl = threadIdx.x >> 5, c = threadIdx.x & 31;
    int ty = (node_type[n0 + nl] == 0) ? 0 : 1;
    const float* W = Wh + ty * (256 * 32);
    float acc = bh[ty * 32 + c];
#pragma unroll 8
    for (int k = 0; k < 256; ++k) acc += sm[nl][k] * W[k * 32 + c];
    sx[nl][c] = acc;
    __syncthreads();
    float xl = 0.f;
#pragma unroll 8
    for (int cc = 0; cc < 32; ++cc) xl += sx[nl][cc] * Wlin[cc * 32 + c];
    xlin[(long)(n0 + nl) * 32 + c] = (_Float16)xl;
    if (threadIdx.x < 64) {
        int nl2 = threadIdx.x >> 3, h = threadIdx.x & 7;
        float a1 = 0.f, a2 = 0.f;
#pragma unroll 8
        for (int cc = 0; cc < 32; ++cc) {
            float xv = sx[nl2][cc];
            a1 += xv * Watt[cc * 8 + h];
            a2 += xv * Watt[(32 + cc) * 8 + h];
        }
        adst[(long)(n0 + nl2) * 8 + h] = a1;
        asrc[(long)(n0 + nl2) * 8 + h] = a2;
    }
}

// ---------------- edge aggregation + LN1 (one wave per node) ----------------
__global__ __launch_bounds__(256) void k_edge_ln1(
    const int* __restrict__ off, const int* __restrict__ src_p,
    const float* __restrict__ tperm, const float* __restrict__ C,
    const float* __restrict__ adst, const float* __restrict__ asrc,
    const _Float16* __restrict__ xlin, const float* __restrict__ m_in,
    const float* __restrict__ g1, const float* __restrict__ b1,
    _Float16* __restrict__ m1h) {
    __shared__ float sC[104];
    if (threadIdx.x < 104) sC[threadIdx.x] = C[threadIdx.x];
    __syncthreads();
    int n = blockIdx.x * 4 + (threadIdx.x >> 6);
    int lane = threadIdx.x & 63;
    long base = off[n];
    int deg = off[n + 1] - (int)base;
    int h = lane & 7;
    float adst_h = adst[(long)n * 8 + h];
    float mx = -1e30f;
    for (int i = lane >> 3; i < deg; i += 8) {
        long ei = base + i;
        int p = src_p[ei];
        int s = p & 0xFFFFF, lt = p >> 20;
        float t = tperm[ei];
        float attc = sC[16 + lt * 8 + h] + t * (t > 0.f ? sC[h] : sC[8 + h]);
        float lg = leakyf(adst_h + asrc[(long)s * 8 + h] + attc);
        mx = fmaxf(mx, lg);
    }
    mx = fmaxf(mx, __shfl_xor(mx, 8));
    mx = fmaxf(mx, __shfl_xor(mx, 16));
    mx = fmaxf(mx, __shfl_xor(mx, 32));
    int hv = lane >> 5, lc = lane & 31;
    float linP = sC[40 + lc], linM = sC[72 + lc];
    float ssum = 0.f;
    float acc[8] = {0.f, 0.f, 0.f, 0.f, 0.f, 0.f, 0.f, 0.f};
    int deg2 = (deg + 1) & ~1;
    for (int i2 = hv; i2 < deg2; i2 += 2) {
        bool valid = i2 < deg;
        long ei = base + (valid ? i2 : (deg - 1));
        int p = src_p[ei];
        int s = p & 0xFFFFF, lt = p >> 20;
        float t = tperm[ei];
        float attc = sC[16 + lt * 8 + h] + t * (t > 0.f ? sC[h] : sC[8 + h]);
        float lg = adst_h + asrc[(long)s * 8 + h] + attc;
        float w = valid ? __expf(leakyf(lg) - mx) : 0.f;
        float msg = (float)xlin[(long)s * 32 + lc] + t * (t > 0.f ? linP : linM);
        if (lc < 8) ssum += w;
#pragma unroll
        for (int hh = 0; hh < 8; ++hh) {
            float whh = __shfl(w, (hv << 5) + hh);
            acc[hh] += whh * msg;
        }
    }
#pragma unroll
    for (int hh = 0; hh < 8; ++hh) acc[hh] += __shfl_xor(acc[hh], 32);
    ssum += __shfl_xor(ssum, 32);
    float v[8];
    float s1 = 0.f, s2 = 0.f;
#pragma unroll
    for (int hh = 0; hh < 8; ++hh) {
        float sh = __shfl(ssum, hh);
        float o = acc[hh] / (sh + 1e-16f);
        float vv = o + m_in[(long)n * 256 + hh * 32 + lc];
        v[hh] = vv;
        s1 += vv;
        s2 += vv * vv;
    }
#pragma unroll
    for (int d = 1; d < 64; d <<= 1) { s1 += __shfl_xor(s1, d); s2 += __shfl_xor(s2, d); }
    float mu = s1 * (1.f / 512.f);
    float var = s2 * (1.f / 512.f) - mu * mu;
    float rs = rsqrtf(var + 1e-5f);
    if (hv == 0) {
#pragma unroll
        for (int hh = 0; hh < 8; ++hh) {
            int col = hh * 32 + lc;
            float o = (v[hh] - mu) * rs * g1[col] + b1[col];
            m1h[(long)n * 256 + col] = (_Float16)o;
        }
    }
}

// ---------------- FFN1: relu(A[M,256] @ W1T[1024,256]^T + b1) -> fp16 [M,1024] --------
// XCD-remapped grid; A panel per row-block read once through one XCD's L2.
__global__ __launch_bounds__(256) void k_ffn1(const _Float16* __restrict__ A,
                                              const _Float16* __restrict__ BT,
                                              const float* __restrict__ bias,
                                              _Float16* __restrict__ out,
                                              int M, int nRP) {
    __shared__ _Float16 sA[128 * 64];
    __shared__ _Float16 sB[128 * 64];
    __shared__ float sEpi[4][16][68];  // per-wave 16x64 fp32, +4 pad
    int bid = blockIdx.x;
    int xcd = bid & 7;
    int jj = bid >> 3;
    int ct = jj & 7;
    int rp = xcd + 8 * (jj >> 3);
    if (rp >= nRP) return;
    const int rowBase = rp * 128;
    const int colBase = ct * 128;
    const int tid = threadIdx.x, wid = tid >> 6, lane = tid & 63;
    const int wm = (wid >> 1) * 64, wn = (wid & 1) * 64;

    floatx4 acc[4][4];
    floatx4 zz = {0.f, 0.f, 0.f, 0.f};
#pragma unroll
    for (int i = 0; i < 4; ++i)
#pragma unroll
        for (int j = 0; j < 4; ++j) acc[i][j] = zz;

    for (int k0 = 0; k0 < 256; k0 += 64) {
#pragma unroll
        for (int it = 0; it < 4; ++it) {
            int Ci = it * 256 + tid;
            int row = Ci >> 3, ch = Ci & 7;
            int gr = rowBase + row;
            if (gr > M - 1) gr = M - 1;
            gload16(A + (long)gr * 256 + k0 + ((ch ^ (row & 7)) * 8),
                    &sA[(it * 256 + wid * 64) * 8]);
        }
#pragma unroll
        for (int it = 0; it < 4; ++it) {
            int Ci = it * 256 + tid;
            int row = Ci >> 3, ch = Ci & 7;
            gload16(BT + (long)(colBase + row) * 256 + k0 + ((ch ^ (row & 7)) * 8),
                    &sB[(it * 256 + wid * 64) * 8]);
        }
        __syncthreads();
#pragma unroll
        for (int kk = 0; kk < 2; ++kk) {
            half8 af[4], bf[4];
#pragma unroll
            for (int i = 0; i < 4; ++i) {
                int row = wm + i * 16 + (lane & 15);
                int ch = (kk * 4 + (lane >> 4)) ^ (row & 7);
                af[i] = *(const half8*)&sA[row * 64 + ch * 8];
            }
#pragma unroll
            for (int j = 0; j < 4; ++j) {
                int row = wn + j * 16 + (lane & 15);
                int ch = (kk * 4 + (lane >> 4)) ^ (row & 7);
                bf[j] = *(const half8*)&sB[row * 64 + ch * 8];
            }
#pragma unroll
            for (int i = 0; i < 4; ++i)
#pragma unroll
                for (int j = 0; j < 4; ++j)
                    acc[i][j] = __builtin_amdgcn_mfma_f32_16x16x32_f16(af[i], bf[j], acc[i][j], 0, 0, 0);
        }
        __syncthreads();
    }
    // epilogue: per-wave LDS transpose -> full-line packed fp16 stores
#pragma unroll
    for (int i = 0; i < 4; ++i) {
#pragma unroll
        for (int j = 0; j < 4; ++j)
#pragma unroll
            for (int q = 0; q < 4; ++q)
                sEpi[wid][(lane >> 4) * 4 + q][j * 16 + (lane & 15)] = acc[i][j][q];
        __asm__ volatile("s_waitcnt lgkmcnt(0)");
#pragma unroll
        for (int it = 0; it < 4; ++it) {
            int r16 = it * 4 + (lane >> 4);
            float4 vv = *(const float4*)&sEpi[wid][r16][(lane & 15) * 4];
            int grow = rowBase + wm + i * 16 + r16;
            int gcol = colBase + wn + (lane & 15) * 4;
            if (grow < M) {
                float4 bv = *(const float4*)&bias[gcol];
                float o0 = vv.x + bv.x, o1 = vv.y + bv.y, o2 = vv.z + bv.z, o3 = vv.w + bv.w;
                o0 = o0 > 0.f ? o0 : 0.f;
                o1 = o1 > 0.f ? o1 : 0.f;
                o2 = o2 > 0.f ? o2 : 0.f;
                o3 = o3 > 0.f ? o3 : 0.f;
                half4v hv;
                hv[0] = (_Float16)o0; hv[1] = (_Float16)o1;
                hv[2] = (_Float16)o2; hv[3] = (_Float16)o3;
                *(half4v*)&out[(long)grow * 1024 + gcol] = hv;
            }
        }
        __syncthreads();
    }
}

// ---------------- FFN2 fused: LN2(A[M,1024] @ W2T[256,1024]^T + b2 + resid) -> fp32 ----
__global__ __launch_bounds__(512) void k_ffn2(const _Float16* __restrict__ A,
                                              const _Float16* __restrict__ BT,
                                              const float* __restrict__ bias,
                                              const _Float16* __restrict__ resid,
                                              const float* __restrict__ g2,
                                              const float* __restrict__ b2,
                                              float* __restrict__ outp, int M) {
    __shared__ _Float16 sA[128 * 64];
    __shared__ _Float16 sB[256 * 64];
    __shared__ float sS1[2][128], sS2[2][128];
    const int rowBase = blockIdx.x * 128;
    const int tid = threadIdx.x, wid = tid >> 6, lane = tid & 63;
    const int wm = (wid >> 1) * 32, wn = (wid & 1) * 128, cg = wid & 1;

    floatx4 acc[2][8];
    floatx4 zz = {0.f, 0.f, 0.f, 0.f};
#pragma unroll
    for (int i = 0; i < 2; ++i)
#pragma unroll
        for (int j = 0; j < 8; ++j) acc[i][j] = zz;

    for (int k0 = 0; k0 < 1024; k0 += 64) {
#pragma unroll
        for (int it = 0; it < 2; ++it) {
            int Ci = it * 512 + tid;
            int row = Ci >> 3, ch = Ci & 7;
            int gr = rowBase + row;
            if (gr > M - 1) gr = M - 1;
            gload16(A + (long)gr * 1024 + k0 + ((ch ^ (row & 7)) * 8),
                    &sA[(it * 512 + wid * 64) * 8]);
        }
#pragma unroll
        for (int it = 0; it < 4; ++it) {
            int Ci = it * 512 + tid;
            int row = Ci >> 3, ch = Ci & 7;
            gload16(BT + (long)row * 1024 + k0 + ((ch ^ (row & 7)) * 8),
                    &sB[(it * 512 + wid * 64) * 8]);
        }
        __syncthreads();
#pragma unroll
        for (int kk = 0; kk < 2; ++kk) {
            half8 af[2], bf[8];
#pragma unroll
            for (int i = 0; i < 2; ++i) {
                int row = wm + i * 16 + (lane & 15);
                int ch = (kk * 4 + (lane >> 4)) ^ (row & 7);
                af[i] = *(const half8*)&sA[row * 64 + ch * 8];
            }
#pragma unroll
            for (int j = 0; j < 8; ++j) {
                int row = wn + j * 16 + (lane & 15);
                int ch = (kk * 4 + (lane >> 4)) ^ (row & 7);
                bf[j] = *(const half8*)&sB[row * 64 + ch * 8];
            }
#pragma unroll
            for (int i = 0; i < 2; ++i)
#pragma unroll
                for (int j = 0; j < 8; ++j)
                    acc[i][j] = __builtin_amdgcn_mfma_f32_16x16x32_f16(af[i], bf[j], acc[i][j], 0, 0, 0);
        }
        __syncthreads();
    }
    // phase 1: bias + residual, row partial sums
#pragma unroll
    for (int i = 0; i < 2; ++i) {
#pragma unroll
        for (int q = 0; q < 4; ++q) {
            int rl = wm + i * 16 + (lane >> 4) * 4 + q;
            long grow = rowBase + rl;
            long gr = grow > M - 1 ? M - 1 : grow;
            float s1 = 0.f, s2 = 0.f;
#pragma unroll
            for (int j = 0; j < 8; ++j) {
                int gcol = wn + j * 16 + (lane & 15);
                float v = acc[i][j][q] + bias[gcol] + (float)resid[gr * 256 + gcol];
                acc[i][j][q] = v;
                s1 += v;
                s2 += v * v;
            }
#pragma unroll
            for (int d = 1; d < 16; d <<= 1) {
                s1 += __shfl_xor(s1, d);
                s2 += __shfl_xor(s2, d);
            }
            if ((lane & 15) == 0) {
                sS1[cg][rl] = s1;
                sS2[cg][rl] = s2;
            }
        }
    }
    __syncthreads();
    // phase 2: normalize + store (full-line fp32)
#pragma unroll
    for (int i = 0; i < 2; ++i) {
#pragma unroll
        for (int q = 0; q < 4; ++q) {
            int rl = wm + i * 16 + (lane >> 4) * 4 + q;
            long grow = rowBase + rl;
            if (grow < M) {
                float t1 = sS1[0][rl] + sS1[1][rl];
                float t2 = sS2[0][rl] + sS2[1][rl];
                float mu = t1 * (1.f / 256.f);
                float var = t2 * (1.f / 256.f) - mu * mu;
                float rs = rsqrtf(var + 1e-5f);
#pragma unroll
                for (int j = 0; j < 8; ++j) {
                    int gcol = wn + j * 16 + (lane & 15);
                    outp[grow * 256 + gcol] = (acc[i][j][q] - mu) * rs * g2[gcol] + b2[gcol];
                }
            }
        }
    }
}

__global__ void k_fail(float* out) {
    if (threadIdx.x == 0 && blockIdx.x == 0) out[0] = 2.0e6f;
}

extern "C" void kernel_launch(void* const* d_in, const int* in_sizes, int n_in,
                              void* d_out, int out_size, void* d_ws, size_t ws_size,
                              hipStream_t stream) {
    const float* x = (const float*)d_in[0];
    const int* ei = (const int*)d_in[1];
    const float* edge_attr = (const float*)d_in[2];
    const int* node_type = (const int*)d_in[3];
    const int* link_type = (const int*)d_in[4];
    const float* Wh = (const float*)d_in[5];
    const float* bh = (const float*)d_in[6];
    const float* Et = (const float*)d_in[7];
    const float* Wea = (const float*)d_in[8];
    const float* Watt = (const float*)d_in[9];
    const float* Wlin = (const float*)d_in[10];
    const float* ffn_w1 = (const float*)d_in[11];
    const float* ffn_b1 = (const float*)d_in[12];
    const float* ffn_w2 = (const float*)d_in[13];
    const float* ffn_b2 = (const float*)d_in[14];
    const float* ln1_g = (const float*)d_in[15];
    const float* ln1_b = (const float*)d_in[16];
    const float* ln2_g = (const float*)d_in[17];
    const float* ln2_b = (const float*)d_in[18];
    const int* srcp = ei;
    const int* dstp = ei + Ee;

    size_t o = 0;
    auto carve = [&](size_t bytes) -> void* {
        void* p = (char*)d_ws + o;
        o += (bytes + 255) & ~(size_t)255;
        return p;
    };
    _Float16* m1h = (_Float16*)carve((size_t)Nn * 256 * 2);
    float* adst = (float*)carve((size_t)Nn * 8 * 4);
    float* asrc = (float*)carve((size_t)Nn * 8 * 4);
    _Float16* xlin = (_Float16*)carve((size_t)Nn * 32 * 2);
    int* src_p = (int*)carve((size_t)Ee * 4);
    float* tperm = (float*)carve((size_t)Ee * 4);
    int* off = (int*)carve((size_t)(Nn + 1) * 4);
    int* cnt = (int*)carve((size_t)Nn * 4);
    int* cur = (int*)carve((size_t)Nn * 4);
    _Float16* W1T = (_Float16*)carve((size_t)STEPSn * 256 * 1024 * 2);
    _Float16* W2T = (_Float16*)carve((size_t)STEPSn * 256 * 1024 * 2);
    float* econst = (float*)carve(104 * 4);
    // runtime-sized FFN row chunk: only f1h now = 2048 B/row
    long remain = (long)ws_size - (long)o;
    long ch = remain / 2048;
    ch = (ch / 128) * 128;
    int CH = ch > Nn ? Nn : (int)ch;
    if (CH < 128) {
        k_fail<<<1, 64, 0, stream>>>((float*)d_out);
        return;
    }
    _Float16* f1h = (_Float16*)carve((size_t)CH * 1024 * 2);
    if (o > ws_size) {
        k_fail<<<1, 64, 0, stream>>>((float*)d_out);
        return;
    }

    hipMemsetAsync(cnt, 0, (size_t)Nn * 4, stream);
    hipMemsetAsync(cur, 0, (size_t)Nn * 4, stream);
    k_count<<<3125, 256, 0, stream>>>(dstp, cnt);
    k_scan<<<1, 256, 0, stream>>>(cnt, off);
    k_fill<<<3125, 256, 0, stream>>>(srcp, dstp, edge_attr, link_type, off, cur,
                                     src_p, tperm);
    k_const<<<1, 128, 0, stream>>>(Et, Wea, Watt, Wlin, econst);
    k_wtrans<<<6144, 256, 0, stream>>>(ffn_w1, W1T, 256, 1024);
    k_wtrans<<<6144, 256, 0, stream>>>(ffn_w2, W2T, 1024, 256);

    const float* m_in = x;
    for (int s = 0; s < STEPSn; ++s) {
        k_node_proj<<<Nn / 8, 256, 0, stream>>>(m_in, node_type, Wh, bh, Watt, Wlin,
                                                adst, asrc, xlin);
        k_edge_ln1<<<Nn / 4, 256, 0, stream>>>(off, src_p, tperm, econst, adst, asrc,
                                               xlin, m_in, ln1_g + s * 256, ln1_b + s * 256,
                                               m1h);
        for (int cs = 0; cs < Nn; cs += CH) {
            int cm = (Nn - cs) < CH ? (Nn - cs) : CH;
            int nRP = (cm + 127) / 128;
            int nRPpad = ((nRP + 7) / 8) * 8;
            k_ffn1<<<nRPpad * 8, 256, 0, stream>>>(
                m1h + (size_t)cs * 256, W1T + (size_t)s * 262144,
                ffn_b1 + s * 1024, f1h, cm, nRP);
            k_ffn2<<<nRP, 512, 0, stream>>>(
                f1h, W2T + (size_t)s * 262144, ffn_b2 + s * 256,
                m1h + (size_t)cs * 256, ln2_g + s * 256, ln2_b + s * 256,
                (float*)d_out + (size_t)cs * 256, cm);
        }
        m_in = (const float*)d_out;
    }
}

// Round 4
// 1662.463 us; speedup vs baseline: 1.3494x; 1.0478x over previous
//
#include <hip/hip_runtime.h>

#define Nn 50000
#define Ee 800000
#define STEPSn 6

typedef _Float16 half8 __attribute__((ext_vector_type(8)));
typedef _Float16 half4v __attribute__((ext_vector_type(4)));
typedef float floatx4 __attribute__((ext_vector_type(4)));

typedef __attribute__((address_space(1))) void gvoid_t;
typedef __attribute__((address_space(3))) void svoid_t;

__device__ __forceinline__ float leakyf(float v) { return v > 0.f ? v : 0.2f * v; }

__device__ __forceinline__ void gload16(const void* g, void* l) {
    __builtin_amdgcn_global_load_lds((const gvoid_t*)g, (svoid_t*)l, 16, 0, 0);
}

// ---------------- CSR build ----------------
__global__ void k_count(const int* __restrict__ dst, int* __restrict__ cnt) {
    int e = blockIdx.x * 256 + threadIdx.x;
    if (e < Ee) atomicAdd(&cnt[dst[e]], 1);
}

__global__ void k_scan(const int* __restrict__ cnt, int* __restrict__ off) {
    __shared__ int part[256];
    int t = threadIdx.x;
    const int chunk = (Nn + 255) / 256;
    int beg = t * chunk, end = beg + chunk;
    if (end > Nn) end = Nn;
    if (beg > Nn) beg = Nn;
    int s = 0;
    for (int i = beg; i < end; ++i) s += cnt[i];
    part[t] = s;
    __syncthreads();
    if (t == 0) {
        int run = 0;
        for (int i = 0; i < 256; ++i) { int v = part[i]; part[i] = run; run += v; }
        off[Nn] = run;
    }
    __syncthreads();
    int run = part[t];
    for (int i = beg; i < end; ++i) { off[i] = run; run += cnt[i]; }
}

// fill CSR slots: packed (src | lt<<20, bitcast(edge_attr)) per slot
__global__ void k_fill(const int* __restrict__ src, const int* __restrict__ dst,
                       const float* __restrict__ edge_attr, const int* __restrict__ link_type,
                       const int* __restrict__ off, int* __restrict__ cur,
                       int2* __restrict__ edata) {
    int e = blockIdx.x * 256 + threadIdx.x;
    if (e >= Ee) return;
    int d = dst[e];
    int slot = off[d] + atomicAdd(&cur[d], 1);
    edata[slot] = make_int2(src[e] | (link_type[e] << 20), __float_as_int(edge_attr[e]));
}

// ---------------- tiny per-launch constants ----------------
// C layout: [0:8] attP, [8:16] attM, [16:40] etA (3x8), [40:72] linP, [72:104] linM
__global__ void k_const(const float* __restrict__ Et, const float* __restrict__ Wea,
                        const float* __restrict__ Watt, const float* __restrict__ Wlin,
                        float* __restrict__ C) {
    __shared__ float u[50], v[50];
    int t = threadIdx.x;
    if (t < 50) {
        float w = Wea[t];
        u[t] = w * (w > 0.f ? 1.f : 0.2f);
        v[t] = w * (w < 0.f ? 1.f : 0.2f);
    }
    __syncthreads();
    if (t < 8) {
        float a = 0.f, b = 0.f;
        for (int j = 0; j < 50; ++j) {
            float w = Watt[(74 + j) * 8 + t];
            a += u[j] * w;
            b += v[j] * w;
        }
        C[t] = a;
        C[8 + t] = b;
    } else if (t < 32) {
        int lt = (t - 8) >> 3, h = (t - 8) & 7;
        float a = 0.f;
        for (int j = 0; j < 10; ++j) a += leakyf(Et[lt * 10 + j]) * Watt[(64 + j) * 8 + h];
        C[16 + (t - 8)] = a;
    } else if (t < 64) {
        int c = t - 32;
        float a = 0.f, b = 0.f;
        for (int j = 0; j < 50; ++j) {
            float w = Wlin[(32 + j) * 32 + c];
            a += u[j] * w;
            b += v[j] * w;
        }
        C[40 + c] = a;
        C[72 + c] = b;
    }
}

// ---------------- tiled weight transpose+convert: W [K][NN] fp32 -> WT [NN][K] fp16 ----
__global__ __launch_bounds__(256) void k_wtrans(const float* __restrict__ W,
                                                _Float16* __restrict__ WT,
                                                int K, int NN) {
    __shared__ float tile[64][65];
    int nk = K >> 6, nn = NN >> 6;
    int b = blockIdx.x;
    int s = b / (nk * nn);
    int r = b % (nk * nn);
    int kt = r / nn, nt = r % nn;
    const float* Ws = W + (long)s * K * NN;
    _Float16* WTs = WT + (long)s * K * NN;
    int lrow = threadIdx.x >> 6, lcol = threadIdx.x & 63;
#pragma unroll
    for (int i = 0; i < 16; ++i) {
        int row = i * 4 + lrow;
        tile[row][lcol] = Ws[(long)(kt * 64 + row) * NN + nt * 64 + lcol];
    }
    __syncthreads();
#pragma unroll
    for (int i = 0; i < 16; ++i) {
        int row = i * 4 + lrow;  // n index
        WTs[(long)(nt * 64 + row) * K + kt * 64 + lcol] = (_Float16)tile[lcol][row];
    }
}

// ---------------- per-node projections ----------------
__global__ __launch_bounds__(256) void k_node_proj(
    const float* __restrict__ m, const int* __restrict__ node_type,
    const float* __restrict__ Wh, const float* __restrict__ bh,
    const float* __restrict__ Watt, const float* __restrict__ Wlin,
    float* __restrict__ adst, float* __restrict__ asrc, _Float16* __restrict__ xlin) {
    __shared__ float sm[8][256];
    __shared__ float sx[8][32];
    int n0 = blockIdx.x * 8;
    for (int i = threadIdx.x; i < 8 * 256; i += 256) sm[i >> 8][i & 255] = m[(long)n0 * 256 + i];
    __syncthreads();
    int nl = threadIdx.x >> 5, c = threadIdx.x & 31;
    int ty = (node_type[n0 + nl] == 0) ? 0 : 1;
    const float* W = Wh + ty * (256 * 32);
    float acc = bh[ty * 32 + c];
#pragma unroll 8
    for (int k = 0; k < 256; ++k) acc += sm[nl][k] * W[k * 32 + c];
    sx[nl][c] = acc;
    __syncthreads();
    float xl = 0.f;
#pragma unroll 8
    for (int cc = 0; cc < 32; ++cc) xl += sx[nl][cc] * Wlin[cc * 32 + c];
    xlin[(long)(n0 + nl) * 32 + c] = (_Float16)xl;
    if (threadIdx.x < 64) {
        int nl2 = threadIdx.x >> 3, h = threadIdx.x & 7;
        float a1 = 0.f, a2 = 0.f;
#pragma unroll 8
        for (int cc = 0; cc < 32; ++cc) {
            float xv = sx[nl2][cc];
            a1 += xv * Watt[cc * 8 + h];
            a2 += xv * Watt[(32 + cc) * 8 + h];
        }
        adst[(long)(n0 + nl2) * 8 + h] = a1;
        asrc[(long)(n0 + nl2) * 8 + h] = a2;
    }
}

// ---------------- edge aggregation + LN1 (one wave per node, single pass, no max) ------
__global__ __launch_bounds__(256) void k_edge_ln1(
    const int* __restrict__ off, const int2* __restrict__ edata,
    const float* __restrict__ C,
    const float* __restrict__ adst, const float* __restrict__ asrc,
    const _Float16* __restrict__ xlin, const float* __restrict__ m_in,
    const float* __restrict__ g1, const float* __restrict__ b1,
    _Float16* __restrict__ m1h) {
    __shared__ float sC[104];
    if (threadIdx.x < 104) sC[threadIdx.x] = C[threadIdx.x];
    __syncthreads();
    int n = blockIdx.x * 4 + (threadIdx.x >> 6);
    int lane = threadIdx.x & 63;
    long base = off[n];
    int deg = off[n + 1] - (int)base;
    int h = lane & 7;
    int hv = lane >> 5, lc = lane & 31;
    float adst_h = adst[(long)n * 8 + h];
    float linP = sC[40 + lc], linM = sC[72 + lc];
    float ssum = 0.f;
    float acc[8] = {0.f, 0.f, 0.f, 0.f, 0.f, 0.f, 0.f, 0.f};
    int deg2 = (deg + 1) & ~1;
    for (int i2 = hv; i2 < deg2; i2 += 2) {
        bool valid = i2 < deg;
        long ei = base + (valid ? i2 : (deg - 1));
        int2 ed = edata[ei];
        int s = ed.x & 0xFFFFF, lt = ed.x >> 20;
        float t = __int_as_float(ed.y);
        float attc = sC[16 + lt * 8 + h] + t * (t > 0.f ? sC[h] : sC[8 + h]);
        float lg = adst_h + asrc[(long)s * 8 + h] + attc;
        float w = valid ? __expf(leakyf(lg)) : 0.f;  // softmax is shift-invariant; |lg|<~4
        float msg = (float)xlin[(long)s * 32 + lc] + t * (t > 0.f ? linP : linM);
        if (lc < 8) ssum += w;
#pragma unroll
        for (int hh = 0; hh < 8; ++hh) {
            float whh = __shfl(w, (hv << 5) + hh);
            acc[hh] += whh * msg;
        }
    }
#pragma unroll
    for (int hh = 0; hh < 8; ++hh) acc[hh] += __shfl_xor(acc[hh], 32);
    ssum += __shfl_xor(ssum, 32);
    float v[8];
    float s1 = 0.f, s2 = 0.f;
#pragma unroll
    for (int hh = 0; hh < 8; ++hh) {
        float sh = __shfl(ssum, hh);
        float o = acc[hh] / (sh + 1e-16f);
        float vv = o + m_in[(long)n * 256 + hh * 32 + lc];
        v[hh] = vv;
        s1 += vv;
        s2 += vv * vv;
    }
#pragma unroll
    for (int d = 1; d < 64; d <<= 1) { s1 += __shfl_xor(s1, d); s2 += __shfl_xor(s2, d); }
    float mu = s1 * (1.f / 512.f);
    float var = s2 * (1.f / 512.f) - mu * mu;
    float rs = rsqrtf(var + 1e-5f);
    if (hv == 0) {
#pragma unroll
        for (int hh = 0; hh < 8; ++hh) {
            int col = hh * 32 + lc;
            float o = (v[hh] - mu) * rs * g1[col] + b1[col];
            m1h[(long)n * 256 + col] = (_Float16)o;
        }
    }
}

// ---------------- FFN1: relu(A[M,256] @ W1T[1024,256]^T + b1) -> fp16 [M,1024] --------
__global__ __launch_bounds__(256) void k_ffn1(const _Float16* __restrict__ A,
                                              const _Float16* __restrict__ BT,
                                              const float* __restrict__ bias,
                                              _Float16* __restrict__ out,
                                              int M, int nRP) {
    __shared__ _Float16 sA[128 * 64];
    __shared__ _Float16 sB[128 * 64];
    __shared__ float sEpi[4][16][68];
    int bid = blockIdx.x;
    int xcd = bid & 7;
    int jj = bid >> 3;
    int ct = jj & 7;
    int rp = xcd + 8 * (jj >> 3);
    if (rp >= nRP) return;
    const int rowBase = rp * 128;
    const int colBase = ct * 128;
    const int tid = threadIdx.x, wid = tid >> 6, lane = tid & 63;
    const int wm = (wid >> 1) * 64, wn = (wid & 1) * 64;

    floatx4 acc[4][4];
    floatx4 zz = {0.f, 0.f, 0.f, 0.f};
#pragma unroll
    for (int i = 0; i < 4; ++i)
#pragma unroll
        for (int j = 0; j < 4; ++j) acc[i][j] = zz;

    for (int k0 = 0; k0 < 256; k0 += 64) {
#pragma unroll
        for (int it = 0; it < 4; ++it) {
            int Ci = it * 256 + tid;
            int row = Ci >> 3, ch = Ci & 7;
            int gr = rowBase + row;
            if (gr > M - 1) gr = M - 1;
            gload16(A + (long)gr * 256 + k0 + ((ch ^ (row & 7)) * 8),
                    &sA[(it * 256 + wid * 64) * 8]);
        }
#pragma unroll
        for (int it = 0; it < 4; ++it) {
            int Ci = it * 256 + tid;
            int row = Ci >> 3, ch = Ci & 7;
            gload16(BT + (long)(colBase + row) * 256 + k0 + ((ch ^ (row & 7)) * 8),
                    &sB[(it * 256 + wid * 64) * 8]);
        }
        __syncthreads();
#pragma unroll
        for (int kk = 0; kk < 2; ++kk) {
            half8 af[4], bf[4];
#pragma unroll
            for (int i = 0; i < 4; ++i) {
                int row = wm + i * 16 + (lane & 15);
                int ch = (kk * 4 + (lane >> 4)) ^ (row & 7);
                af[i] = *(const half8*)&sA[row * 64 + ch * 8];
            }
#pragma unroll
            for (int j = 0; j < 4; ++j) {
                int row = wn + j * 16 + (lane & 15);
                int ch = (kk * 4 + (lane >> 4)) ^ (row & 7);
                bf[j] = *(const half8*)&sB[row * 64 + ch * 8];
            }
#pragma unroll
            for (int i = 0; i < 4; ++i)
#pragma unroll
                for (int j = 0; j < 4; ++j)
                    acc[i][j] = __builtin_amdgcn_mfma_f32_16x16x32_f16(af[i], bf[j], acc[i][j], 0, 0, 0);
        }
        __syncthreads();
    }
    // epilogue: per-wave LDS transpose -> full-line packed fp16 stores
#pragma unroll
    for (int i = 0; i < 4; ++i) {
#pragma unroll
        for (int j = 0; j < 4; ++j)
#pragma unroll
            for (int q = 0; q < 4; ++q)
                sEpi[wid][(lane >> 4) * 4 + q][j * 16 + (lane & 15)] = acc[i][j][q];
        __asm__ volatile("s_waitcnt lgkmcnt(0)");
#pragma unroll
        for (int it = 0; it < 4; ++it) {
            int r16 = it * 4 + (lane >> 4);
            float4 vv = *(const float4*)&sEpi[wid][r16][(lane & 15) * 4];
            int grow = rowBase + wm + i * 16 + r16;
            int gcol = colBase + wn + (lane & 15) * 4;
            if (grow < M) {
                float4 bv = *(const float4*)&bias[gcol];
                float o0 = vv.x + bv.x, o1 = vv.y + bv.y, o2 = vv.z + bv.z, o3 = vv.w + bv.w;
                o0 = o0 > 0.f ? o0 : 0.f;
                o1 = o1 > 0.f ? o1 : 0.f;
                o2 = o2 > 0.f ? o2 : 0.f;
                o3 = o3 > 0.f ? o3 : 0.f;
                half4v hv;
                hv[0] = (_Float16)o0; hv[1] = (_Float16)o1;
                hv[2] = (_Float16)o2; hv[3] = (_Float16)o3;
                *(half4v*)&out[(long)grow * 1024 + gcol] = hv;
            }
        }
        __asm__ volatile("s_waitcnt lgkmcnt(0)");
    }
}

// ---------------- FFN2 fused: LN2(A[M,1024] @ W2T[256,1024]^T + b2 + resid) -> fp32 ----
__global__ __launch_bounds__(512) void k_ffn2(const _Float16* __restrict__ A,
                                              const _Float16* __restrict__ BT,
                                              const float* __restrict__ bias,
                                              const _Float16* __restrict__ resid,
                                              const float* __restrict__ g2,
                                              const float* __restrict__ b2,
                                              float* __restrict__ outp, int M) {
    __shared__ _Float16 sA[128 * 64];
    __shared__ _Float16 sB[256 * 64];
    __shared__ float sS1[2][128], sS2[2][128];
    const int rowBase = blockIdx.x * 128;
    const int tid = threadIdx.x, wid = tid >> 6, lane = tid & 63;
    const int wm = (wid >> 1) * 32, wn = (wid & 1) * 128, cg = wid & 1;

    floatx4 acc[2][8];
    floatx4 zz = {0.f, 0.f, 0.f, 0.f};
#pragma unroll
    for (int i = 0; i < 2; ++i)
#pragma unroll
        for (int j = 0; j < 8; ++j) acc[i][j] = zz;

    for (int k0 = 0; k0 < 1024; k0 += 64) {
#pragma unroll
        for (int it = 0; it < 2; ++it) {
            int Ci = it * 512 + tid;
            int row = Ci >> 3, ch = Ci & 7;
            int gr = rowBase + row;
            if (gr > M - 1) gr = M - 1;
            gload16(A + (long)gr * 1024 + k0 + ((ch ^ (row & 7)) * 8),
                    &sA[(it * 512 + wid * 64) * 8]);
        }
#pragma unroll
        for (int it = 0; it < 4; ++it) {
            int Ci = it * 512 + tid;
            int row = Ci >> 3, ch = Ci & 7;
            gload16(BT + (long)row * 1024 + k0 + ((ch ^ (row & 7)) * 8),
                    &sB[(it * 512 + wid * 64) * 8]);
        }
        __syncthreads();
#pragma unroll
        for (int kk = 0; kk < 2; ++kk) {
            half8 af[2], bf[8];
#pragma unroll
            for (int i = 0; i < 2; ++i) {
                int row = wm + i * 16 + (lane & 15);
                int ch = (kk * 4 + (lane >> 4)) ^ (row & 7);
                af[i] = *(const half8*)&sA[row * 64 + ch * 8];
            }
#pragma unroll
            for (int j = 0; j < 8; ++j) {
                int row = wn + j * 16 + (lane & 15);
                int ch = (kk * 4 + (lane >> 4)) ^ (row & 7);
                bf[j] = *(const half8*)&sB[row * 64 + ch * 8];
            }
#pragma unroll
            for (int i = 0; i < 2; ++i)
#pragma unroll
                for (int j = 0; j < 8; ++j)
                    acc[i][j] = __builtin_amdgcn_mfma_f32_16x16x32_f16(af[i], bf[j], acc[i][j], 0, 0, 0);
        }
        __syncthreads();
    }
    // phase 1: bias + residual, row partial sums
#pragma unroll
    for (int i = 0; i < 2; ++i) {
#pragma unroll
        for (int q = 0; q < 4; ++q) {
            int rl = wm + i * 16 + (lane >> 4) * 4 + q;
            long grow = rowBase + rl;
            long gr = grow > M - 1 ? M - 1 : grow;
            float s1 = 0.f, s2 = 0.f;
#pragma unroll
            for (int j = 0; j < 8; ++j) {
                int gcol = wn + j * 16 + (lane & 15);
                float v = acc[i][j][q] + bias[gcol] + (float)resid[gr * 256 + gcol];
                acc[i][j][q] = v;
                s1 += v;
                s2 += v * v;
            }
#pragma unroll
            for (int d = 1; d < 16; d <<= 1) {
                s1 += __shfl_xor(s1, d);
                s2 += __shfl_xor(s2, d);
            }
            if ((lane & 15) == 0) {
                sS1[cg][rl] = s1;
                sS2[cg][rl] = s2;
            }
        }
    }
    __syncthreads();
    // phase 2: normalize + store
#pragma unroll
    for (int i = 0; i < 2; ++i) {
#pragma unroll
        for (int q = 0; q < 4; ++q) {
            int rl = wm + i * 16 + (lane >> 4) * 4 + q;
            long grow = rowBase + rl;
            if (grow < M) {
                float t1 = sS1[0][rl] + sS1[1][rl];
                float t2 = sS2[0][rl] + sS2[1][rl];
                float mu = t1 * (1.f / 256.f);
                float var = t2 * (1.f / 256.f) - mu * mu;
                float rs = rsqrtf(var + 1e-5f);
#pragma unroll
                for (int j = 0; j < 8; ++j) {
                    int gcol = wn + j * 16 + (lane & 15);
                    outp[grow * 256 + gcol] = (acc[i][j][q] - mu) * rs * g2[gcol] + b2[gcol];
                }
            }
        }
    }
}

__global__ void k_fail(float* out) {
    if (threadIdx.x == 0 && blockIdx.x == 0) out[0] = 2.0e6f;
}

extern "C" void kernel_launch(void* const* d_in, const int* in_sizes, int n_in,
                              void* d_out, int out_size, void* d_ws, size_t ws_size,
                              hipStream_t stream) {
    const float* x = (const float*)d_in[0];
    const int* ei = (const int*)d_in[1];
    const float* edge_attr = (const float*)d_in[2];
    const int* node_type = (const int*)d_in[3];
    const int* link_type = (const int*)d_in[4];
    const float* Wh = (const float*)d_in[5];
    const float* bh = (const float*)d_in[6];
    const float* Et = (const float*)d_in[7];
    const float* Wea = (const float*)d_in[8];
    const float* Watt = (const float*)d_in[9];
    const float* Wlin = (const float*)d_in[10];
    const float* ffn_w1 = (const float*)d_in[11];
    const float* ffn_b1 = (const float*)d_in[12];
    const float* ffn_w2 = (const float*)d_in[13];
    const float* ffn_b2 = (const float*)d_in[14];
    const float* ln1_g = (const float*)d_in[15];
    const float* ln1_b = (const float*)d_in[16];
    const float* ln2_g = (const float*)d_in[17];
    const float* ln2_b = (const float*)d_in[18];
    const int* srcp = ei;
    const int* dstp = ei + Ee;

    size_t o = 0;
    auto carve = [&](size_t bytes) -> void* {
        void* p = (char*)d_ws + o;
        o += (bytes + 255) & ~(size_t)255;
        return p;
    };
    _Float16* m1h = (_Float16*)carve((size_t)Nn * 256 * 2);
    float* adst = (float*)carve((size_t)Nn * 8 * 4);
    float* asrc = (float*)carve((size_t)Nn * 8 * 4);
    _Float16* xlin = (_Float16*)carve((size_t)Nn * 32 * 2);
    int2* edata = (int2*)carve((size_t)Ee * 8);
    int* off = (int*)carve((size_t)(Nn + 1) * 4);
    int* cnt = (int*)carve((size_t)Nn * 4);
    int* cur = (int*)carve((size_t)Nn * 4);
    _Float16* W1T = (_Float16*)carve((size_t)STEPSn * 256 * 1024 * 2);
    _Float16* W2T = (_Float16*)carve((size_t)STEPSn * 256 * 1024 * 2);
    float* econst = (float*)carve(104 * 4);
    long remain = (long)ws_size - (long)o;
    long ch = remain / 2048;
    ch = (ch / 128) * 128;
    int CH = ch > Nn ? Nn : (int)ch;
    if (CH < 128) {
        k_fail<<<1, 64, 0, stream>>>((float*)d_out);
        return;
    }
    _Float16* f1h = (_Float16*)carve((size_t)CH * 1024 * 2);
    if (o > ws_size) {
        k_fail<<<1, 64, 0, stream>>>((float*)d_out);
        return;
    }

    hipMemsetAsync(cnt, 0, (size_t)Nn * 4, stream);
    hipMemsetAsync(cur, 0, (size_t)Nn * 4, stream);
    k_count<<<3125, 256, 0, stream>>>(dstp, cnt);
    k_scan<<<1, 256, 0, stream>>>(cnt, off);
    k_fill<<<3125, 256, 0, stream>>>(srcp, dstp, edge_attr, link_type, off, cur, edata);
    k_const<<<1, 128, 0, stream>>>(Et, Wea, Watt, Wlin, econst);
    k_wtrans<<<STEPSn * 64, 256, 0, stream>>>(ffn_w1, W1T, 256, 1024);
    k_wtrans<<<STEPSn * 64, 256, 0, stream>>>(ffn_w2, W2T, 1024, 256);

    const float* m_in = x;
    for (int s = 0; s < STEPSn; ++s) {
        k_node_proj<<<Nn / 8, 256, 0, stream>>>(m_in, node_type, Wh, bh, Watt, Wlin,
                                                adst, asrc, xlin);
        k_edge_ln1<<<Nn / 4, 256, 0, stream>>>(off, edata, econst, adst, asrc,
                                               xlin, m_in, ln1_g + s * 256, ln1_b + s * 256,
                                               m1h);
        for (int cs = 0; cs < Nn; cs += CH) {
            int cm = (Nn - cs) < CH ? (Nn - cs) : CH;
            int nRP = (cm + 127) / 128;
            int nRPpad = ((nRP + 7) / 8) * 8;
            k_ffn1<<<nRPpad * 8, 256, 0, stream>>>(
                m1h + (size_t)cs * 256, W1T + (size_t)s * 262144,
                ffn_b1 + s * 1024, f1h, cm, nRP);
            k_ffn2<<<nRP, 512, 0, stream>>>(
                f1h, W2T + (size_t)s * 262144, ffn_b2 + s * 256,
                m1h + (size_t)cs * 256, ln2_g + s * 256, ln2_b + s * 256,
                (float*)d_out + (size_t)cs * 256, cm);
        }
        m_in = (const float*)d_out;
    }
}

// Round 6
// 1295.521 us; speedup vs baseline: 1.7316x; 1.2832x over previous
//
#include <hip/hip_runtime.h>

#define Nn 50000
#define Ee 800000
#define STEPSn 6
#define NP 49  // ceil(Nn/1024)

typedef _Float16 half8 __attribute__((ext_vector_type(8)));
typedef _Float16 half4v __attribute__((ext_vector_type(4)));
typedef float floatx4 __attribute__((ext_vector_type(4)));

typedef __attribute__((address_space(1))) void gvoid_t;
typedef __attribute__((address_space(3))) void svoid_t;

__device__ __forceinline__ float leakyf(float v) { return v > 0.f ? v : 0.2f * v; }

__device__ __forceinline__ void gload16(const void* g, void* l) {
    __builtin_amdgcn_global_load_lds((const gvoid_t*)g, (svoid_t*)l, 16, 0, 0);
}

// ---------------- CSR build ----------------
__global__ void k_count(const int* __restrict__ dst, int* __restrict__ cnt) {
    int e = blockIdx.x * 256 + threadIdx.x;
    if (e < Ee) atomicAdd(&cnt[dst[e]], 1);
}

// partial sums over 1024-element chunks
__global__ __launch_bounds__(256) void k_scan1(const int* __restrict__ cnt,
                                               int* __restrict__ part) {
    int b = blockIdx.x, t = threadIdx.x;
    int s = 0;
#pragma unroll
    for (int j = 0; j < 4; ++j) {
        int idx = b * 1024 + j * 256 + t;
        if (idx < Nn) s += cnt[idx];
    }
#pragma unroll
    for (int d = 1; d < 64; d <<= 1) s += __shfl_xor(s, d);
    __shared__ int ws[4];
    if ((t & 63) == 0) ws[t >> 6] = s;
    __syncthreads();
    if (t == 0) part[b] = ws[0] + ws[1] + ws[2] + ws[3];
}

// exclusive scan of NP partials (single wave)
__global__ void k_scan2(const int* __restrict__ part, int* __restrict__ pref,
                        int* __restrict__ offN) {
    int t = threadIdx.x;  // 64
    int v = (t < NP) ? part[t] : 0;
    int p = v;
#pragma unroll
    for (int d = 1; d < 64; d <<= 1) {
        int u = __shfl_up(p, d);
        if (t >= d) p += u;
    }
    if (t < NP) pref[t] = p - v;
    if (t == 63) offN[0] = p;
}

// per-chunk exclusive scan + global offset
__global__ __launch_bounds__(256) void k_scan3(const int* __restrict__ cnt,
                                               const int* __restrict__ pref,
                                               int* __restrict__ off) {
    __shared__ int wsum[4];
    int b = blockIdx.x, t = threadIdx.x;
    int base = b * 1024;
    int v[4];
    int s = 0;
#pragma unroll
    for (int j = 0; j < 4; ++j) {
        int idx = base + t * 4 + j;
        v[j] = (idx < Nn) ? cnt[idx] : 0;
        s += v[j];
    }
    int lane = t & 63, w = t >> 6;
    int ps = s;
#pragma unroll
    for (int d = 1; d < 64; d <<= 1) {
        int u = __shfl_up(ps, d);
        if (lane >= d) ps += u;
    }
    if (lane == 63) wsum[w] = ps;
    __syncthreads();
    int woff = 0;
    for (int i = 0; i < w; ++i) woff += wsum[i];
    int ex = pref[b] + woff + ps - s;
#pragma unroll
    for (int j = 0; j < 4; ++j) {
        int idx = base + t * 4 + j;
        if (idx < Nn) off[idx] = ex;
        ex += v[j];
    }
}

// fill CSR slots: packed (src | lt<<20, bitcast(edge_attr)) per slot
__global__ void k_fill(const int* __restrict__ src, const int* __restrict__ dst,
                       const float* __restrict__ edge_attr, const int* __restrict__ link_type,
                       const int* __restrict__ off, int* __restrict__ cur,
                       int2* __restrict__ edata) {
    int e = blockIdx.x * 256 + threadIdx.x;
    if (e >= Ee) return;
    int d = dst[e];
    int slot = off[d] + atomicAdd(&cur[d], 1);
    edata[slot] = make_int2(src[e] | (link_type[e] << 20), __float_as_int(edge_attr[e]));
}

// ---------------- tiny per-launch constants ----------------
// C layout: [0:8] attP, [8:16] attM, [16:40] etA (3x8), [40:72] linP, [72:104] linM
__global__ void k_const(const float* __restrict__ Et, const float* __restrict__ Wea,
                        const float* __restrict__ Watt, const float* __restrict__ Wlin,
                        float* __restrict__ C) {
    __shared__ float u[50], v[50];
    int t = threadIdx.x;
    if (t < 50) {
        float w = Wea[t];
        u[t] = w * (w > 0.f ? 1.f : 0.2f);
        v[t] = w * (w < 0.f ? 1.f : 0.2f);
    }
    __syncthreads();
    if (t < 8) {
        float a = 0.f, b = 0.f;
        for (int j = 0; j < 50; ++j) {
            float w = Watt[(74 + j) * 8 + t];
            a += u[j] * w;
            b += v[j] * w;
        }
        C[t] = a;
        C[8 + t] = b;
    } else if (t < 32) {
        int lt = (t - 8) >> 3, h = (t - 8) & 7;
        float a = 0.f;
        for (int j = 0; j < 10; ++j) a += leakyf(Et[lt * 10 + j]) * Watt[(64 + j) * 8 + h];
        C[16 + (t - 8)] = a;
    } else if (t < 64) {
        int c = t - 32;
        float a = 0.f, b = 0.f;
        for (int j = 0; j < 50; ++j) {
            float w = Wlin[(32 + j) * 32 + c];
            a += u[j] * w;
            b += v[j] * w;
        }
        C[40 + c] = a;
        C[72 + c] = b;
    }
}

// ---------------- combined node-proj weights: Wcmb[128][256] fp16, bcmb[96] ----------
// row n<96: ty=n/48, c=n%48; cols: [0,32) Wlin, [32,40) Watt dst, [40,48) Watt src
__global__ void k_comb(const float* __restrict__ Wh, const float* __restrict__ bh,
                       const float* __restrict__ Watt, const float* __restrict__ Wlin,
                       _Float16* __restrict__ Wcmb, float* __restrict__ bcmb) {
    int n = blockIdx.x;   // 0..127
    int k = threadIdx.x;  // 0..255
    if (n >= 96) {
        Wcmb[n * 256 + k] = (_Float16)0.f;
        return;
    }
    int ty = n / 48, c = n % 48;
    float a = 0.f;
    for (int kk = 0; kk < 32; ++kk) {
        float wsel;
        if (c < 32) wsel = Wlin[kk * 32 + c];
        else if (c < 40) wsel = Watt[kk * 8 + (c - 32)];
        else wsel = Watt[(32 + kk) * 8 + (c - 40)];
        a += Wh[ty * 8192 + k * 32 + kk] * wsel;
    }
    Wcmb[n * 256 + k] = (_Float16)a;
    if (k == 0) {
        float b = 0.f;
        for (int kk = 0; kk < 32; ++kk) {
            float wsel;
            if (c < 32) wsel = Wlin[kk * 32 + c];
            else if (c < 40) wsel = Watt[kk * 8 + (c - 32)];
            else wsel = Watt[(32 + kk) * 8 + (c - 40)];
            b += bh[ty * 32 + kk] * wsel;
        }
        bcmb[n] = b;
    }
}

// ---------------- x fp32 -> fp16 ----------------
__global__ void k_cvt(const float* __restrict__ x, _Float16* __restrict__ mh) {
    long i = ((long)blockIdx.x * 256 + threadIdx.x) * 4;
    if (i < (long)Nn * 256) {
        float4 v = *(const float4*)(x + i);
        half4v h;
        h[0] = (_Float16)v.x; h[1] = (_Float16)v.y;
        h[2] = (_Float16)v.z; h[3] = (_Float16)v.w;
        *(half4v*)(mh + i) = h;
    }
}

// ---------------- tiled weight transpose+convert: W [K][NN] fp32 -> WT [NN][K] fp16 ----
__global__ __launch_bounds__(256) void k_wtrans(const float* __restrict__ W,
                                                _Float16* __restrict__ WT,
                                                int K, int NN) {
    __shared__ float tile[64][65];
    int nk = K >> 6, nn = NN >> 6;
    int b = blockIdx.x;
    int s = b / (nk * nn);
    int r = b % (nk * nn);
    int kt = r / nn, nt = r % nn;
    const float* Ws = W + (long)s * K * NN;
    _Float16* WTs = WT + (long)s * K * NN;
    int lrow = threadIdx.x >> 6, lcol = threadIdx.x & 63;
#pragma unroll
    for (int i = 0; i < 16; ++i) {
        int row = i * 4 + lrow;
        tile[row][lcol] = Ws[(long)(kt * 64 + row) * NN + nt * 64 + lcol];
    }
    __syncthreads();
#pragma unroll
    for (int i = 0; i < 16; ++i) {
        int row = i * 4 + lrow;  // n index
        WTs[(long)(nt * 64 + row) * K + kt * 64 + lcol] = (_Float16)tile[lcol][row];
    }
}

// ---------------- node projections via MFMA: mh[M,256] @ Wcmb[128,256]^T ------------
__global__ __launch_bounds__(256) void k_node_proj2(
    const _Float16* __restrict__ mh, const int* __restrict__ node_type,
    const _Float16* __restrict__ Wcmb, const float* __restrict__ bcmb,
    float* __restrict__ adst, float* __restrict__ asrc,
    _Float16* __restrict__ xlin, int M) {
    __shared__ _Float16 sA[128 * 64];
    __shared__ _Float16 sB[128 * 64];
    __shared__ float sEpi[128][100];
    const int rowBase = blockIdx.x * 128;
    const int tid = threadIdx.x, wid = tid >> 6, lane = tid & 63;
    const int wm = (wid >> 1) * 64, wn = (wid & 1) * 64;

    floatx4 acc[4][4];
    floatx4 zz = {0.f, 0.f, 0.f, 0.f};
#pragma unroll
    for (int i = 0; i < 4; ++i)
#pragma unroll
        for (int j = 0; j < 4; ++j) acc[i][j] = zz;

    for (int k0 = 0; k0 < 256; k0 += 64) {
#pragma unroll
        for (int it = 0; it < 4; ++it) {
            int Ci = it * 256 + tid;
            int row = Ci >> 3, ch = Ci & 7;
            int gr = rowBase + row;
            if (gr > M - 1) gr = M - 1;
            gload16(mh + (long)gr * 256 + k0 + ((ch ^ (row & 7)) * 8),
                    &sA[(it * 256 + wid * 64) * 8]);
        }
#pragma unroll
        for (int it = 0; it < 4; ++it) {
            int Ci = it * 256 + tid;
            int row = Ci >> 3, ch = Ci & 7;
            gload16(Wcmb + (long)row * 256 + k0 + ((ch ^ (row & 7)) * 8),
                    &sB[(it * 256 + wid * 64) * 8]);
        }
        __syncthreads();
#pragma unroll
        for (int kk = 0; kk < 2; ++kk) {
            half8 af[4], bf[4];
#pragma unroll
            for (int i = 0; i < 4; ++i) {
                int row = wm + i * 16 + (lane & 15);
                int ch = (kk * 4 + (lane >> 4)) ^ (row & 7);
                af[i] = *(const half8*)&sA[row * 64 + ch * 8];
            }
#pragma unroll
            for (int j = 0; j < 4; ++j) {
                int row = wn + j * 16 + (lane & 15);
                int ch = (kk * 4 + (lane >> 4)) ^ (row & 7);
                bf[j] = *(const half8*)&sB[row * 64 + ch * 8];
            }
#pragma unroll
            for (int i = 0; i < 4; ++i)
#pragma unroll
                for (int j = 0; j < 4; ++j)
                    acc[i][j] = __builtin_amdgcn_mfma_f32_16x16x32_f16(af[i], bf[j], acc[i][j], 0, 0, 0);
        }
        __syncthreads();
    }
    // dump to LDS for type-select epilogue
#pragma unroll
    for (int i = 0; i < 4; ++i)
#pragma unroll
        for (int j = 0; j < 4; ++j) {
            int col = wn + j * 16 + (lane & 15);
            if (col < 96) {
#pragma unroll
                for (int q = 0; q < 4; ++q)
                    sEpi[wm + i * 16 + (lane >> 4) * 4 + q][col] = acc[i][j][q];
            }
        }
    __syncthreads();
    for (int idx = tid; idx < 128 * 32; idx += 256) {
        int r = idx >> 5, c = idx & 31;
        int gr = rowBase + r;
        if (gr < M) {
            int ty = (node_type[gr] != 0) ? 1 : 0;
            int sc = ty * 48 + c;
            xlin[(long)gr * 32 + c] = (_Float16)(sEpi[r][sc] + bcmb[sc]);
        }
    }
    for (int idx = tid; idx < 128 * 8; idx += 256) {
        int r = idx >> 3, hh = idx & 7;
        int gr = rowBase + r;
        if (gr < M) {
            int ty = (node_type[gr] != 0) ? 1 : 0;
            adst[(long)gr * 8 + hh] = sEpi[r][ty * 48 + 32 + hh] + bcmb[ty * 48 + 32 + hh];
            asrc[(long)gr * 8 + hh] = sEpi[r][ty * 48 + 40 + hh] + bcmb[ty * 48 + 40 + hh];
        }
    }
}

// ---------------- edge aggregation + LN1 (one wave/node, pipelined gathers) ----------
__global__ __launch_bounds__(256) void k_edge_ln1(
    const int* __restrict__ off, const int2* __restrict__ edata,
    const float* __restrict__ C,
    const float* __restrict__ adst, const float* __restrict__ asrc,
    const _Float16* __restrict__ xlin, const float* __restrict__ m_in,
    const float* __restrict__ g1, const float* __restrict__ b1,
    _Float16* __restrict__ m1h) {
    __shared__ float sC[104];
    if (threadIdx.x < 104) sC[threadIdx.x] = C[threadIdx.x];
    __syncthreads();
    int n = blockIdx.x * 4 + (threadIdx.x >> 6);
    int lane = threadIdx.x & 63;
    long base = off[n];
    int deg = off[n + 1] - (int)base;
    int h = lane & 7;
    int hv = lane >> 5, lc = lane & 31;
    float adst_h = adst[(long)n * 8 + h];
    float linP = sC[40 + lc], linM = sC[72 + lc];
    float ssum = 0.f;
    float acc[8] = {0.f, 0.f, 0.f, 0.f, 0.f, 0.f, 0.f, 0.f};
    int deg2 = (deg + 1) & ~1;
    // software-pipelined: prefetch next edge's data during current compute
    int i2 = hv;
    int2 edA = make_int2(0, 0);
    float asA = 0.f, xlA = 0.f;
    if (i2 < deg2) {
        long ei = base + (i2 < deg ? i2 : deg - 1);
        edA = edata[ei];
        int sA = edA.x & 0xFFFFF;
        asA = asrc[(long)sA * 8 + h];
        xlA = (float)xlin[(long)sA * 32 + lc];
    }
    while (i2 < deg2) {
        int i2n = i2 + 2;
        int2 edB = make_int2(0, 0);
        float asB = 0.f, xlB = 0.f;
        if (i2n < deg2) {
            long ein = base + (i2n < deg ? i2n : deg - 1);
            edB = edata[ein];
            int sB = edB.x & 0xFFFFF;
            asB = asrc[(long)sB * 8 + h];
            xlB = (float)xlin[(long)sB * 32 + lc];
        }
        bool valid = i2 < deg;
        int lt = edA.x >> 20;
        float t = __int_as_float(edA.y);
        float attc = sC[16 + lt * 8 + h] + t * (t > 0.f ? sC[h] : sC[8 + h]);
        float lg = adst_h + asA + attc;
        float w = valid ? __expf(leakyf(lg)) : 0.f;  // shift-invariant softmax; |lg| small
        float msg = xlA + t * (t > 0.f ? linP : linM);
        if (lc < 8) ssum += w;
        int wbits = __float_as_int(w);
        // broadcast lane HH within each 32-lane group (BitMode offset: or_mask=HH, and=0)
#define BCAST(HH)                                                                         \
        {                                                                                 \
            float whh = __int_as_float(__builtin_amdgcn_ds_swizzle(wbits, (HH) << 5));    \
            acc[HH] += whh * msg;                                                         \
        }
        BCAST(0) BCAST(1) BCAST(2) BCAST(3) BCAST(4) BCAST(5) BCAST(6) BCAST(7)
#undef BCAST
        edA = edB; asA = asB; xlA = xlB;
        i2 = i2n;
    }
#pragma unroll
    for (int hh = 0; hh < 8; ++hh) acc[hh] += __shfl_xor(acc[hh], 32);
    ssum += __shfl_xor(ssum, 32);
    float v[8];
    float s1 = 0.f, s2 = 0.f;
#pragma unroll
    for (int hh = 0; hh < 8; ++hh) {
        float sh = __shfl(ssum, hh);
        float o = acc[hh] / (sh + 1e-16f);
        float vv = o + m_in[(long)n * 256 + hh * 32 + lc];
        v[hh] = vv;
        s1 += vv;
        s2 += vv * vv;
    }
#pragma unroll
    for (int d = 1; d < 64; d <<= 1) { s1 += __shfl_xor(s1, d); s2 += __shfl_xor(s2, d); }
    float mu = s1 * (1.f / 512.f);
    float var = s2 * (1.f / 512.f) - mu * mu;
    float rs = rsqrtf(var + 1e-5f);
    if (hv == 0) {
#pragma unroll
        for (int hh = 0; hh < 8; ++hh) {
            int col = hh * 32 + lc;
            float o = (v[hh] - mu) * rs * g1[col] + b1[col];
            m1h[(long)n * 256 + col] = (_Float16)o;
        }
    }
}

// ---------------- FFN1: relu(A[M,256] @ W1T[1024,256]^T + b1) -> fp16 [M,1024] --------
__global__ __launch_bounds__(256) void k_ffn1(const _Float16* __restrict__ A,
                                              const _Float16* __restrict__ BT,
                                              const float* __restrict__ bias,
                                              _Float16* __restrict__ out,
                                              int M, int nRP) {
    __shared__ _Float16 sA[128 * 64];
    __shared__ _Float16 sB[128 * 64];
    __shared__ float sEpi[4][16][68];
    int bid = blockIdx.x;
    int xcd = bid & 7;
    int jj = bid >> 3;
    int ct = jj & 7;
    int rp = xcd + 8 * (jj >> 3);
    if (rp >= nRP) return;
    const int rowBase = rp * 128;
    const int colBase = ct * 128;
    const int tid = threadIdx.x, wid = tid >> 6, lane = tid & 63;
    const int wm = (wid >> 1) * 64, wn = (wid & 1) * 64;

    floatx4 acc[4][4];
    floatx4 zz = {0.f, 0.f, 0.f, 0.f};
#pragma unroll
    for (int i = 0; i < 4; ++i)
#pragma unroll
        for (int j = 0; j < 4; ++j) acc[i][j] = zz;

    for (int k0 = 0; k0 < 256; k0 += 64) {
#pragma unroll
        for (int it = 0; it < 4; ++it) {
            int Ci = it * 256 + tid;
            int row = Ci >> 3, ch = Ci & 7;
            int gr = rowBase + row;
            if (gr > M - 1) gr = M - 1;
            gload16(A + (long)gr * 256 + k0 + ((ch ^ (row & 7)) * 8),
                    &sA[(it * 256 + wid * 64) * 8]);
        }
#pragma unroll
        for (int it = 0; it < 4; ++it) {
            int Ci = it * 256 + tid;
            int row = Ci >> 3, ch = Ci & 7;
            gload16(BT + (long)(colBase + row) * 256 + k0 + ((ch ^ (row & 7)) * 8),
                    &sB[(it * 256 + wid * 64) * 8]);
        }
        __syncthreads();
#pragma unroll
        for (int kk = 0; kk < 2; ++kk) {
            half8 af[4], bf[4];
#pragma unroll
            for (int i = 0; i < 4; ++i) {
                int row = wm + i * 16 + (lane & 15);
                int ch = (kk * 4 + (lane >> 4)) ^ (row & 7);
                af[i] = *(const half8*)&sA[row * 64 + ch * 8];
            }
#pragma unroll
            for (int j = 0; j < 4; ++j) {
                int row = wn + j * 16 + (lane & 15);
                int ch = (kk * 4 + (lane >> 4)) ^ (row & 7);
                bf[j] = *(const half8*)&sB[row * 64 + ch * 8];
            }
#pragma unroll
            for (int i = 0; i < 4; ++i)
#pragma unroll
                for (int j = 0; j < 4; ++j)
                    acc[i][j] = __builtin_amdgcn_mfma_f32_16x16x32_f16(af[i], bf[j], acc[i][j], 0, 0, 0);
        }
        __syncthreads();
    }
    // epilogue: per-wave LDS transpose -> full-line packed fp16 stores
#pragma unroll
    for (int i = 0; i < 4; ++i) {
#pragma unroll
        for (int j = 0; j < 4; ++j)
#pragma unroll
            for (int q = 0; q < 4; ++q)
                sEpi[wid][(lane >> 4) * 4 + q][j * 16 + (lane & 15)] = acc[i][j][q];
        __asm__ volatile("s_waitcnt lgkmcnt(0)");
#pragma unroll
        for (int it = 0; it < 4; ++it) {
            int r16 = it * 4 + (lane >> 4);
            float4 vv = *(const float4*)&sEpi[wid][r16][(lane & 15) * 4];
            int grow = rowBase + wm + i * 16 + r16;
            int gcol = colBase + wn + (lane & 15) * 4;
            if (grow < M) {
                float4 bv = *(const float4*)&bias[gcol];
                float o0 = vv.x + bv.x, o1 = vv.y + bv.y, o2 = vv.z + bv.z, o3 = vv.w + bv.w;
                o0 = o0 > 0.f ? o0 : 0.f;
                o1 = o1 > 0.f ? o1 : 0.f;
                o2 = o2 > 0.f ? o2 : 0.f;
                o3 = o3 > 0.f ? o3 : 0.f;
                half4v hv;
                hv[0] = (_Float16)o0; hv[1] = (_Float16)o1;
                hv[2] = (_Float16)o2; hv[3] = (_Float16)o3;
                *(half4v*)&out[(long)grow * 1024 + gcol] = hv;
            }
        }
        __asm__ volatile("s_waitcnt lgkmcnt(0)");
    }
}

// ---------------- FFN2 fused: LN2(A@W2T + b2 + resid) -> fp32 out + fp16 copy --------
__global__ __launch_bounds__(512) void k_ffn2(const _Float16* __restrict__ A,
                                              const _Float16* __restrict__ BT,
                                              const float* __restrict__ bias,
                                              const _Float16* __restrict__ resid,
                                              const float* __restrict__ g2,
                                              const float* __restrict__ b2,
                                              float* __restrict__ outp,
                                              _Float16* __restrict__ outh, int M) {
    __shared__ _Float16 sA[128 * 64];
    __shared__ _Float16 sB[256 * 64];
    __shared__ float sS1[2][128], sS2[2][128];
    const int rowBase = blockIdx.x * 128;
    const int tid = threadIdx.x, wid = tid >> 6, lane = tid & 63;
    const int wm = (wid >> 1) * 32, wn = (wid & 1) * 128, cg = wid & 1;

    floatx4 acc[2][8];
    floatx4 zz = {0.f, 0.f, 0.f, 0.f};
#pragma unroll
    for (int i = 0; i < 2; ++i)
#pragma unroll
        for (int j = 0; j < 8; ++j) acc[i][j] = zz;

    for (int k0 = 0; k0 < 1024; k0 += 64) {
#pragma unroll
        for (int it = 0; it < 2; ++it) {
            int Ci = it * 512 + tid;
            int row = Ci >> 3, ch = Ci & 7;
            int gr = rowBase + row;
            if (gr > M - 1) gr = M - 1;
            gload16(A + (long)gr * 1024 + k0 + ((ch ^ (row & 7)) * 8),
                    &sA[(it * 512 + wid * 64) * 8]);
        }
#pragma unroll
        for (int it = 0; it < 4; ++it) {
            int Ci = it * 512 + tid;
            int row = Ci >> 3, ch = Ci & 7;
            gload16(BT + (long)row * 1024 + k0 + ((ch ^ (row & 7)) * 8),
                    &sB[(it * 512 + wid * 64) * 8]);
        }
        __syncthreads();
#pragma unroll
        for (int kk = 0; kk < 2; ++kk) {
            half8 af[2], bf[8];
#pragma unroll
            for (int i = 0; i < 2; ++i) {
                int row = wm + i * 16 + (lane & 15);
                int ch = (kk * 4 + (lane >> 4)) ^ (row & 7);
                af[i] = *(const half8*)&sA[row * 64 + ch * 8];
            }
#pragma unroll
            for (int j = 0; j < 8; ++j) {
                int row = wn + j * 16 + (lane & 15);
                int ch = (kk * 4 + (lane >> 4)) ^ (row & 7);
                bf[j] = *(const half8*)&sB[row * 64 + ch * 8];
            }
#pragma unroll
            for (int i = 0; i < 2; ++i)
#pragma unroll
                for (int j = 0; j < 8; ++j)
                    acc[i][j] = __builtin_amdgcn_mfma_f32_16x16x32_f16(af[i], bf[j], acc[i][j], 0, 0, 0);
        }
        __syncthreads();
    }
    // phase 1: bias + residual, row partial sums
#pragma unroll
    for (int i = 0; i < 2; ++i) {
#pragma unroll
        for (int q = 0; q < 4; ++q) {
            int rl = wm + i * 16 + (lane >> 4) * 4 + q;
            long grow = rowBase + rl;
            long gr = grow > M - 1 ? M - 1 : grow;
            float s1 = 0.f, s2 = 0.f;
#pragma unroll
            for (int j = 0; j < 8; ++j) {
                int gcol = wn + j * 16 + (lane & 15);
                float v = acc[i][j][q] + bias[gcol] + (float)resid[gr * 256 + gcol];
                acc[i][j][q] = v;
                s1 += v;
                s2 += v * v;
            }
#pragma unroll
            for (int d = 1; d < 16; d <<= 1) {
                s1 += __shfl_xor(s1, d);
                s2 += __shfl_xor(s2, d);
            }
            if ((lane & 15) == 0) {
                sS1[cg][rl] = s1;
                sS2[cg][rl] = s2;
            }
        }
    }
    __syncthreads();
    // phase 2: normalize + store
#pragma unroll
    for (int i = 0; i < 2; ++i) {
#pragma unroll
        for (int q = 0; q < 4; ++q) {
            int rl = wm + i * 16 + (lane >> 4) * 4 + q;
            long grow = rowBase + rl;
            if (grow < M) {
                float t1 = sS1[0][rl] + sS1[1][rl];
                float t2 = sS2[0][rl] + sS2[1][rl];
                float mu = t1 * (1.f / 256.f);
                float var = t2 * (1.f / 256.f) - mu * mu;
                float rs = rsqrtf(var + 1e-5f);
#pragma unroll
                for (int j = 0; j < 8; ++j) {
                    int gcol = wn + j * 16 + (lane & 15);
                    float o = (acc[i][j][q] - mu) * rs * g2[gcol] + b2[gcol];
                    outp[grow * 256 + gcol] = o;
                    outh[grow * 256 + gcol] = (_Float16)o;
                }
            }
        }
    }
}

__global__ void k_fail(float* out) {
    if (threadIdx.x == 0 && blockIdx.x == 0) out[0] = 2.0e6f;
}

extern "C" void kernel_launch(void* const* d_in, const int* in_sizes, int n_in,
                              void* d_out, int out_size, void* d_ws, size_t ws_size,
                              hipStream_t stream) {
    const float* x = (const float*)d_in[0];
    const int* ei = (const int*)d_in[1];
    const float* edge_attr = (const float*)d_in[2];
    const int* node_type = (const int*)d_in[3];
    const int* link_type = (const int*)d_in[4];
    const float* Wh = (const float*)d_in[5];
    const float* bh = (const float*)d_in[6];
    const float* Et = (const float*)d_in[7];
    const float* Wea = (const float*)d_in[8];
    const float* Watt = (const float*)d_in[9];
    const float* Wlin = (const float*)d_in[10];
    const float* ffn_w1 = (const float*)d_in[11];
    const float* ffn_b1 = (const float*)d_in[12];
    const float* ffn_w2 = (const float*)d_in[13];
    const float* ffn_b2 = (const float*)d_in[14];
    const float* ln1_g = (const float*)d_in[15];
    const float* ln1_b = (const float*)d_in[16];
    const float* ln2_g = (const float*)d_in[17];
    const float* ln2_b = (const float*)d_in[18];
    const int* srcp = ei;
    const int* dstp = ei + Ee;

    size_t o = 0;
    auto carve = [&](size_t bytes) -> void* {
        void* p = (char*)d_ws + o;
        o += (bytes + 255) & ~(size_t)255;
        return p;
    };
    _Float16* m1h = (_Float16*)carve((size_t)Nn * 256 * 2);
    _Float16* mh = (_Float16*)carve((size_t)Nn * 256 * 2);
    float* adst = (float*)carve((size_t)Nn * 8 * 4);
    float* asrc = (float*)carve((size_t)Nn * 8 * 4);
    _Float16* xlin = (_Float16*)carve((size_t)Nn * 32 * 2);
    int2* edata = (int2*)carve((size_t)Ee * 8);
    int* off = (int*)carve((size_t)(Nn + 1) * 4);
    int* cnt = (int*)carve((size_t)Nn * 4);
    int* cur = (int*)carve((size_t)Nn * 4);
    int* part = (int*)carve(64 * 4);
    int* pref = (int*)carve(64 * 4);
    _Float16* W1T = (_Float16*)carve((size_t)STEPSn * 256 * 1024 * 2);
    _Float16* W2T = (_Float16*)carve((size_t)STEPSn * 256 * 1024 * 2);
    _Float16* Wcmb = (_Float16*)carve(128 * 256 * 2);
    float* bcmb = (float*)carve(128 * 4);
    float* econst = (float*)carve(104 * 4);
    long remain = (long)ws_size - (long)o;
    long ch = remain / 2048;
    ch = (ch / 128) * 128;
    int CH = ch > Nn ? Nn : (int)ch;
    if (CH < 128) {
        k_fail<<<1, 64, 0, stream>>>((float*)d_out);
        return;
    }
    _Float16* f1h = (_Float16*)carve((size_t)CH * 1024 * 2);
    if (o > ws_size) {
        k_fail<<<1, 64, 0, stream>>>((float*)d_out);
        return;
    }

    hipMemsetAsync(cnt, 0, (size_t)Nn * 4, stream);
    hipMemsetAsync(cur, 0, (size_t)Nn * 4, stream);
    k_count<<<3125, 256, 0, stream>>>(dstp, cnt);
    k_scan1<<<NP, 256, 0, stream>>>(cnt, part);
    k_scan2<<<1, 64, 0, stream>>>(part, pref, off + Nn);
    k_scan3<<<NP, 256, 0, stream>>>(cnt, pref, off);
    k_fill<<<3125, 256, 0, stream>>>(srcp, dstp, edge_attr, link_type, off, cur, edata);
    k_const<<<1, 128, 0, stream>>>(Et, Wea, Watt, Wlin, econst);
    k_comb<<<128, 256, 0, stream>>>(Wh, bh, Watt, Wlin, Wcmb, bcmb);
    k_cvt<<<12500, 256, 0, stream>>>(x, mh);
    k_wtrans<<<STEPSn * 64, 256, 0, stream>>>(ffn_w1, W1T, 256, 1024);
    k_wtrans<<<STEPSn * 64, 256, 0, stream>>>(ffn_w2, W2T, 1024, 256);

    const float* m_in = x;
    for (int s = 0; s < STEPSn; ++s) {
        k_node_proj2<<<(Nn + 127) / 128, 256, 0, stream>>>(mh, node_type, Wcmb, bcmb,
                                                           adst, asrc, xlin, Nn);
        k_edge_ln1<<<Nn / 4, 256, 0, stream>>>(off, edata, econst, adst, asrc,
                                               xlin, m_in, ln1_g + s * 256, ln1_b + s * 256,
                                               m1h);
        for (int cs = 0; cs < Nn; cs += CH) {
            int cm = (Nn - cs) < CH ? (Nn - cs) : CH;
            int nRP = (cm + 127) / 128;
            int nRPpad = ((nRP + 7) / 8) * 8;
            k_ffn1<<<nRPpad * 8, 256, 0, stream>>>(
                m1h + (size_t)cs * 256, W1T + (size_t)s * 262144,
                ffn_b1 + s * 1024, f1h, cm, nRP);
            k_ffn2<<<nRP, 512, 0, stream>>>(
                f1h, W2T + (size_t)s * 262144, ffn_b2 + s * 256,
                m1h + (size_t)cs * 256, ln2_g + s * 256, ln2_b + s * 256,
                (float*)d_out + (size_t)cs * 256, mh + (size_t)cs * 256, cm);
        }
        m_in = (const float*)d_out;
    }
}